// Round 3
// baseline (607.199 us; speedup 1.0000x reference)
//
#include <hip/hip_runtime.h>

// ---------------- CSR build ----------------
__global__ void hist_kernel(const int* __restrict__ dst, int* __restrict__ deg, int E) {
  int e = blockIdx.x * blockDim.x + threadIdx.x;
  if (e < E) atomicAdd(&deg[dst[e]], 1);
}

__global__ void dinv_kernel(const int* __restrict__ deg, float* __restrict__ dinv, int n) {
  int i = blockIdx.x * blockDim.x + threadIdx.x;
  if (i < n) dinv[i] = rsqrtf((float)(deg[i] + 1));  // +1 self loop
}

__global__ void partial_sum_kernel(const int* __restrict__ cnt, int* __restrict__ bsum, int n) {
  __shared__ int s[256];
  int i = blockIdx.x * 256 + threadIdx.x;
  s[threadIdx.x] = (i < n) ? cnt[i] : 0;
  __syncthreads();
  for (int off = 128; off > 0; off >>= 1) {
    if (threadIdx.x < off) s[threadIdx.x] += s[threadIdx.x + off];
    __syncthreads();
  }
  if (threadIdx.x == 0) bsum[blockIdx.x] = s[0];
}

__global__ void scan_bsum_kernel(const int* __restrict__ bsum, int* __restrict__ bexcl,
                                 int nb, int* __restrict__ rowptr_last) {
  __shared__ int s[256];
  int t = threadIdx.x;
  int v = (t < nb) ? bsum[t] : 0;
  s[t] = v;
  __syncthreads();
  for (int off = 1; off < 256; off <<= 1) {
    int add = (t >= off) ? s[t - off] : 0;
    __syncthreads();
    s[t] += add;
    __syncthreads();
  }
  if (t < nb) bexcl[t] = s[t] - v;
  if (t == 255) *rowptr_last = s[255];
}

__global__ void rowptr_kernel(const int* __restrict__ cnt, const int* __restrict__ bexcl,
                              int* __restrict__ rowptr, int n) {
  __shared__ int s[256];
  int i = blockIdx.x * 256 + threadIdx.x;
  int t = threadIdx.x;
  int v = (i < n) ? cnt[i] : 0;
  s[t] = v;
  __syncthreads();
  for (int off = 1; off < 256; off <<= 1) {
    int add = (t >= off) ? s[t - off] : 0;
    __syncthreads();
    s[t] += add;
    __syncthreads();
  }
  if (i < n) rowptr[i] = bexcl[blockIdx.x] + s[t] - v;
}

__global__ void fill_kernel(const int* __restrict__ src, const int* __restrict__ dst,
                            const float* __restrict__ dinv, const int* __restrict__ rowptr,
                            int* __restrict__ cursor, int* __restrict__ col,
                            float* __restrict__ wv, int E) {
  int e = blockIdx.x * blockDim.x + threadIdx.x;
  if (e >= E) return;
  int s = src[e], d = dst[e];
  int p = atomicAdd(&cursor[d], 1);
  int slot = rowptr[d] + p;
  col[slot] = s;
  wv[slot] = dinv[s] * dinv[d];
}

// ---------------- aggregation: agg[i] = dinv[i]^2*h[i] + sum_e wv*h[col] ----------------
template <int D>
__global__ __launch_bounds__(256) void aggregate_kernel(
    const float* __restrict__ h, const int* __restrict__ rowptr, const int* __restrict__ col,
    const float* __restrict__ wv, const float* __restrict__ dinv, float* __restrict__ out, int n) {
  int wid = (blockIdx.x * 256 + threadIdx.x) >> 6;  // one wave per node
  int lane = threadIdx.x & 63;
  if (wid >= n) return;
  float di = dinv[wid];
  float sl = di * di;
  int beg = rowptr[wid], end = rowptr[wid + 1];
  if constexpr (D == 64) {
    float acc = sl * h[(size_t)wid * 64 + lane];
    for (int base = beg; base < end; base += 64) {
      int kk = base + lane;
      int c = 0; float ww = 0.f;
      if (kk < end) { c = col[kk]; ww = wv[kk]; }
      int m = end - base; if (m > 64) m = 64;
      for (int t = 0; t < m; ++t) {
        int cs = __shfl(c, t);
        float ws = __shfl(ww, t);
        acc += ws * h[(size_t)cs * 64 + lane];
      }
    }
    out[(size_t)wid * 64 + lane] = acc;
  } else {
    const float2* h2 = (const float2*)h;
    float2 hv = h2[(size_t)wid * 64 + lane];
    float ax = sl * hv.x, ay = sl * hv.y;
    for (int base = beg; base < end; base += 64) {
      int kk = base + lane;
      int c = 0; float ww = 0.f;
      if (kk < end) { c = col[kk]; ww = wv[kk]; }
      int m = end - base; if (m > 64) m = 64;
      for (int t = 0; t < m; ++t) {
        int cs = __shfl(c, t);
        float ws = __shfl(ww, t);
        float2 v = h2[(size_t)cs * 64 + lane];
        ax += ws * v.x; ay += ws * v.y;
      }
    }
    float2 o; o.x = ax; o.y = ay;
    ((float2*)out)[(size_t)wid * 64 + lane] = o;
  }
}

// ---------------- C = relu(A @ W + b), A[n,K], W[K,128] ----------------
template <int K>
__global__ __launch_bounds__(256) void gemm_bias_relu_kernel(
    const float* __restrict__ A, const float* __restrict__ W, const float* __restrict__ bias,
    float* __restrict__ C, int n) {
  constexpr int BM = 64, BN = 128, BK = 32;
  __shared__ float At[BK][BM + 4];  // transposed A tile, stride 68 floats (16B-aligned rows)
  __shared__ float Ws[BK][BN];
  const int tid = threadIdx.x;
  const int block_row = blockIdx.x * BM;
  const int tr = tid >> 4, tc = tid & 15;
  const int row0 = tr * 4, col0 = tc * 8;
  float acc[4][8] = {};
  for (int kb = 0; kb < K; kb += BK) {
    {  // A tile: 64x32, 8 floats/thread
      int r = tid >> 2;
      int k = (tid & 3) * 8;
      int grow = block_row + r;
      float4 v0 = {0, 0, 0, 0}, v1 = {0, 0, 0, 0};
      if (grow < n) {
        v0 = *(const float4*)&A[(size_t)grow * K + kb + k];
        v1 = *(const float4*)&A[(size_t)grow * K + kb + k + 4];
      }
      At[k + 0][r] = v0.x; At[k + 1][r] = v0.y; At[k + 2][r] = v0.z; At[k + 3][r] = v0.w;
      At[k + 4][r] = v1.x; At[k + 5][r] = v1.y; At[k + 6][r] = v1.z; At[k + 7][r] = v1.w;
    }
    #pragma unroll
    for (int t = 0; t < 4; ++t) {  // W tile: 32x128 = 1024 float4, 4/thread
      int idx4 = tid + t * 256;
      int k = idx4 >> 5;
      int c4 = idx4 & 31;
      *(float4*)&Ws[k][c4 * 4] = *(const float4*)&W[(size_t)(kb + k) * BN + c4 * 4];
    }
    __syncthreads();
    #pragma unroll
    for (int k = 0; k < BK; ++k) {
      float a[4], w[8];
      *(float4*)&a[0] = *(const float4*)&At[k][row0];
      *(float4*)&w[0] = *(const float4*)&Ws[k][col0];
      *(float4*)&w[4] = *(const float4*)&Ws[k][col0 + 4];
      #pragma unroll
      for (int i = 0; i < 4; ++i)
        #pragma unroll
        for (int j = 0; j < 8; ++j)
          acc[i][j] += a[i] * w[j];
    }
    __syncthreads();
  }
  #pragma unroll
  for (int i = 0; i < 4; ++i) {
    int grow = block_row + row0 + i;
    if (grow >= n) continue;
    float o[8];
    #pragma unroll
    for (int j = 0; j < 8; ++j) o[j] = fmaxf(acc[i][j] + bias[col0 + j], 0.f);
    *(float4*)&C[(size_t)grow * BN + col0] = *(float4*)&o[0];
    *(float4*)&C[(size_t)grow * BN + col0 + 4] = *(float4*)&o[4];
  }
}

// ---------------- pooling ----------------
__global__ void pool_kernel(const float* __restrict__ h, const int* __restrict__ batch,
                            float* __restrict__ sums, int n) {
  int idx = blockIdx.x * blockDim.x + threadIdx.x;
  int node = idx >> 5;
  if (node >= n) return;
  int d4 = (idx & 31) * 4;
  int b = batch[node];
  float4 v = *(const float4*)&h[(size_t)node * 128 + d4];
  atomicAdd(&sums[b * 128 + d4 + 0], v.x);
  atomicAdd(&sums[b * 128 + d4 + 1], v.y);
  atomicAdd(&sums[b * 128 + d4 + 2], v.z);
  atomicAdd(&sums[b * 128 + d4 + 3], v.w);
}

__global__ void count_kernel(const int* __restrict__ batch, int* __restrict__ cnt, int n) {
  int i = blockIdx.x * blockDim.x + threadIdx.x;
  if (i < n) atomicAdd(&cnt[batch[i]], 1);
}

// ---------------- per-graph MLP head ----------------
__global__ __launch_bounds__(128) void mlp_kernel(
    const float* __restrict__ sums, const int* __restrict__ cnt,
    const float* __restrict__ lW1, const float* __restrict__ lb1,
    const float* __restrict__ lW2, const float* __restrict__ lb2,
    const float* __restrict__ gamma, const float* __restrict__ beta,
    const float* __restrict__ rm, const float* __restrict__ rv,
    const float* __restrict__ oW, const float* __restrict__ ob,
    float* __restrict__ out, int B) {
  int b = blockIdx.x, t = threadIdx.x;
  __shared__ float p[128], h1[128];
  float c = fmaxf((float)cnt[b], 1.0f);
  p[t] = sums[b * 128 + t] / c;
  __syncthreads();
  float a1 = lb1[t];
  for (int k = 0; k < 128; ++k) a1 += p[k] * lW1[k * 128 + t];
  h1[t] = a1;
  __syncthreads();
  if (t < 64) {
    float a2 = lb2[t];
    for (int k = 0; k < 128; ++k) a2 += h1[k] * lW2[k * 64 + t];
    a2 = (a2 - rm[t]) * gamma[t] * rsqrtf(rv[t] + 1e-5f) + beta[t];
    float hd = fmaxf(a2, 0.f);
    out[B + b * 64 + t] = hd;  // hidden, output 1
    float prod = hd * oW[t];
    #pragma unroll
    for (int off = 32; off > 0; off >>= 1) prod += __shfl_down(prod, off);
    if (t == 0) out[b] = prod + ob[0];  // out, output 0
  }
}

extern "C" void kernel_launch(void* const* d_in, const int* in_sizes, int n_in,
                              void* d_out, int out_size, void* d_ws, size_t ws_size,
                              hipStream_t stream) {
  const float* x = (const float*)d_in[0];
  const int* ei = (const int*)d_in[1];
  const int* batch = (const int*)d_in[2];
  const float* W1 = (const float*)d_in[3];  const float* b1 = (const float*)d_in[4];
  const float* W2 = (const float*)d_in[5];  const float* b2 = (const float*)d_in[6];
  const float* W3 = (const float*)d_in[7];  const float* b3 = (const float*)d_in[8];
  const float* W4 = (const float*)d_in[9];  const float* b4 = (const float*)d_in[10];
  const float* lW1 = (const float*)d_in[11]; const float* lb1 = (const float*)d_in[12];
  const float* lW2 = (const float*)d_in[13]; const float* lb2 = (const float*)d_in[14];
  const float* gamma = (const float*)d_in[15]; const float* beta = (const float*)d_in[16];
  const float* rm = (const float*)d_in[17]; const float* rv = (const float*)d_in[18];
  const float* oW = (const float*)d_in[19]; const float* ob = (const float*)d_in[20];

  const int n = in_sizes[2];
  const int E = in_sizes[1] / 2;
  const int B = out_size / 65;  // out_size = B + B*64
  const int* src = ei;
  const int* dst = ei + E;

  char* ws = (char*)d_ws;
  size_t off = 0;
  auto alloc = [&](size_t bytes) -> void* {
    void* p = ws + off;
    off += (bytes + 255) & ~(size_t)255;
    return p;
  };
  int* deg = (int*)alloc((size_t)n * 4);
  float* dinv = (float*)alloc((size_t)n * 4);
  int* rowptr = (int*)alloc((size_t)(n + 1) * 4);
  int* cursor = (int*)alloc((size_t)n * 4);
  int* bsum = (int*)alloc(256 * 4);
  int* bexcl = (int*)alloc(256 * 4);
  int* col = (int*)alloc((size_t)E * 4);
  float* wv = (float*)alloc((size_t)E * 4);
  float* agg = (float*)alloc((size_t)n * 128 * 4);
  float* hbuf = (float*)alloc((size_t)n * 128 * 4);
  float* sums = (float*)alloc((size_t)B * 128 * 4);
  int* cnt = (int*)alloc((size_t)B * 4);

  hipMemsetAsync(deg, 0, (size_t)n * 4, stream);
  hipMemsetAsync(cursor, 0, (size_t)n * 4, stream);
  hipMemsetAsync(sums, 0, (size_t)B * 128 * 4, stream);
  hipMemsetAsync(cnt, 0, (size_t)B * 4, stream);

  const int nb = (n + 255) / 256;  // 196 blocks <= 256, fits single-block scan
  hist_kernel<<<(E + 255) / 256, 256, 0, stream>>>(dst, deg, E);
  dinv_kernel<<<nb, 256, 0, stream>>>(deg, dinv, n);
  partial_sum_kernel<<<nb, 256, 0, stream>>>(deg, bsum, n);
  scan_bsum_kernel<<<1, 256, 0, stream>>>(bsum, bexcl, nb, rowptr + n);
  rowptr_kernel<<<nb, 256, 0, stream>>>(deg, bexcl, rowptr, n);
  fill_kernel<<<(E + 255) / 256, 256, 0, stream>>>(src, dst, dinv, rowptr, cursor, col, wv, E);

  const int aggblocks = (n + 3) / 4;     // 4 waves (nodes) per block
  const int gemmblocks = (n + 63) / 64;  // 64 rows per block

  aggregate_kernel<64><<<aggblocks, 256, 0, stream>>>(x, rowptr, col, wv, dinv, agg, n);
  gemm_bias_relu_kernel<64><<<gemmblocks, 256, 0, stream>>>(agg, W1, b1, hbuf, n);
  aggregate_kernel<128><<<aggblocks, 256, 0, stream>>>(hbuf, rowptr, col, wv, dinv, agg, n);
  gemm_bias_relu_kernel<128><<<gemmblocks, 256, 0, stream>>>(agg, W2, b2, hbuf, n);
  aggregate_kernel<128><<<aggblocks, 256, 0, stream>>>(hbuf, rowptr, col, wv, dinv, agg, n);
  gemm_bias_relu_kernel<128><<<gemmblocks, 256, 0, stream>>>(agg, W3, b3, hbuf, n);
  aggregate_kernel<128><<<aggblocks, 256, 0, stream>>>(hbuf, rowptr, col, wv, dinv, agg, n);
  gemm_bias_relu_kernel<128><<<gemmblocks, 256, 0, stream>>>(agg, W4, b4, hbuf, n);

  pool_kernel<<<((size_t)n * 32 + 255) / 256, 256, 0, stream>>>(hbuf, batch, sums, n);
  count_kernel<<<nb, 256, 0, stream>>>(batch, cnt, n);
  mlp_kernel<<<B, 128, 0, stream>>>(sums, cnt, lW1, lb1, lW2, lb2, gamma, beta, rm, rv, oW, ob,
                                    (float*)d_out, B);
}

// Round 4
// 504.704 us; speedup vs baseline: 1.2031x; 1.2031x over previous
//
#include <hip/hip_runtime.h>

// ---------------- CSR build ----------------
__global__ void hist_kernel(const int* __restrict__ dst, int* __restrict__ deg, int E) {
  int e = blockIdx.x * blockDim.x + threadIdx.x;
  if (e < E) atomicAdd(&deg[dst[e]], 1);
}

__global__ void dinv_kernel(const int* __restrict__ deg, float* __restrict__ dinv, int n) {
  int i = blockIdx.x * blockDim.x + threadIdx.x;
  if (i < n) dinv[i] = rsqrtf((float)(deg[i] + 1));  // +1 self loop
}

__global__ void partial_sum_kernel(const int* __restrict__ cnt, int* __restrict__ bsum, int n) {
  __shared__ int s[256];
  int i = blockIdx.x * 256 + threadIdx.x;
  s[threadIdx.x] = (i < n) ? cnt[i] : 0;
  __syncthreads();
  for (int off = 128; off > 0; off >>= 1) {
    if (threadIdx.x < off) s[threadIdx.x] += s[threadIdx.x + off];
    __syncthreads();
  }
  if (threadIdx.x == 0) bsum[blockIdx.x] = s[0];
}

__global__ void scan_bsum_kernel(const int* __restrict__ bsum, int* __restrict__ bexcl,
                                 int nb, int* __restrict__ rowptr_last) {
  __shared__ int s[256];
  int t = threadIdx.x;
  int v = (t < nb) ? bsum[t] : 0;
  s[t] = v;
  __syncthreads();
  for (int off = 1; off < 256; off <<= 1) {
    int add = (t >= off) ? s[t - off] : 0;
    __syncthreads();
    s[t] += add;
    __syncthreads();
  }
  if (t < nb) bexcl[t] = s[t] - v;
  if (t == 255) *rowptr_last = s[255];
}

__global__ void rowptr_kernel(const int* __restrict__ cnt, const int* __restrict__ bexcl,
                              int* __restrict__ rowptr, int n) {
  __shared__ int s[256];
  int i = blockIdx.x * 256 + threadIdx.x;
  int t = threadIdx.x;
  int v = (i < n) ? cnt[i] : 0;
  s[t] = v;
  __syncthreads();
  for (int off = 1; off < 256; off <<= 1) {
    int add = (t >= off) ? s[t - off] : 0;
    __syncthreads();
    s[t] += add;
    __syncthreads();
  }
  if (i < n) rowptr[i] = bexcl[blockIdx.x] + s[t] - v;
}

__global__ void fill_kernel(const int* __restrict__ src, const int* __restrict__ dst,
                            const float* __restrict__ dinv, const int* __restrict__ rowptr,
                            int* __restrict__ cursor, int* __restrict__ col,
                            float* __restrict__ wv, int E) {
  int e = blockIdx.x * blockDim.x + threadIdx.x;
  if (e >= E) return;
  int s = src[e], d = dst[e];
  int p = atomicAdd(&cursor[d], 1);
  int slot = rowptr[d] + p;
  col[slot] = s;
  wv[slot] = dinv[s] * dinv[d];
}

// ---------------- aggregation: agg[i] = dinv[i]^2*h[i] + sum_e wv*h[col] ----------------
template <int D>
__global__ __launch_bounds__(256) void aggregate_kernel(
    const float* __restrict__ h, const int* __restrict__ rowptr, const int* __restrict__ col,
    const float* __restrict__ wv, const float* __restrict__ dinv, float* __restrict__ out, int n) {
  int wid = (blockIdx.x * 256 + threadIdx.x) >> 6;  // one wave per node
  int lane = threadIdx.x & 63;
  if (wid >= n) return;
  float di = dinv[wid];
  float sl = di * di;
  int beg = rowptr[wid], end = rowptr[wid + 1];
  if constexpr (D == 64) {
    float acc = sl * h[(size_t)wid * 64 + lane];
    for (int base = beg; base < end; base += 64) {
      int kk = base + lane;
      int c = 0; float ww = 0.f;
      if (kk < end) { c = col[kk]; ww = wv[kk]; }
      int m = end - base; if (m > 64) m = 64;
      for (int t = 0; t < m; ++t) {
        int cs = __shfl(c, t);
        float ws = __shfl(ww, t);
        acc += ws * h[(size_t)cs * 64 + lane];
      }
    }
    out[(size_t)wid * 64 + lane] = acc;
  } else {
    const float2* h2 = (const float2*)h;
    float2 hv = h2[(size_t)wid * 64 + lane];
    float ax = sl * hv.x, ay = sl * hv.y;
    for (int base = beg; base < end; base += 64) {
      int kk = base + lane;
      int c = 0; float ww = 0.f;
      if (kk < end) { c = col[kk]; ww = wv[kk]; }
      int m = end - base; if (m > 64) m = 64;
      for (int t = 0; t < m; ++t) {
        int cs = __shfl(c, t);
        float ws = __shfl(ww, t);
        float2 v = h2[(size_t)cs * 64 + lane];
        ax += ws * v.x; ay += ws * v.y;
      }
    }
    float2 o; o.x = ax; o.y = ay;
    ((float2*)out)[(size_t)wid * 64 + lane] = o;
  }
}

// ---------------- C = relu(A @ W + b), A[n,K], W[K,128] ----------------
template <int K>
__global__ __launch_bounds__(256) void gemm_bias_relu_kernel(
    const float* __restrict__ A, const float* __restrict__ W, const float* __restrict__ bias,
    float* __restrict__ C, int n) {
  constexpr int BM = 64, BN = 128, BK = 32;
  __shared__ float At[BK][BM + 4];  // transposed A tile
  __shared__ float Ws[BK][BN];
  const int tid = threadIdx.x;
  const int block_row = blockIdx.x * BM;
  const int tr = tid >> 4, tc = tid & 15;
  const int row0 = tr * 4, col0 = tc * 8;
  float acc[4][8] = {};
  for (int kb = 0; kb < K; kb += BK) {
    {  // A tile: 64x32, 8 floats/thread
      int r = tid >> 2;
      int k = (tid & 3) * 8;
      int grow = block_row + r;
      float4 v0 = {0, 0, 0, 0}, v1 = {0, 0, 0, 0};
      if (grow < n) {
        v0 = *(const float4*)&A[(size_t)grow * K + kb + k];
        v1 = *(const float4*)&A[(size_t)grow * K + kb + k + 4];
      }
      At[k + 0][r] = v0.x; At[k + 1][r] = v0.y; At[k + 2][r] = v0.z; At[k + 3][r] = v0.w;
      At[k + 4][r] = v1.x; At[k + 5][r] = v1.y; At[k + 6][r] = v1.z; At[k + 7][r] = v1.w;
    }
    #pragma unroll
    for (int t = 0; t < 4; ++t) {  // W tile: 32x128 = 1024 float4, 4/thread
      int idx4 = tid + t * 256;
      int k = idx4 >> 5;
      int c4 = idx4 & 31;
      *(float4*)&Ws[k][c4 * 4] = *(const float4*)&W[(size_t)(kb + k) * BN + c4 * 4];
    }
    __syncthreads();
    #pragma unroll
    for (int k = 0; k < BK; ++k) {
      float a[4], w[8];
      *(float4*)&a[0] = *(const float4*)&At[k][row0];
      *(float4*)&w[0] = *(const float4*)&Ws[k][col0];
      *(float4*)&w[4] = *(const float4*)&Ws[k][col0 + 4];
      #pragma unroll
      for (int i = 0; i < 4; ++i)
        #pragma unroll
        for (int j = 0; j < 8; ++j)
          acc[i][j] += a[i] * w[j];
    }
    __syncthreads();
  }
  #pragma unroll
  for (int i = 0; i < 4; ++i) {
    int grow = block_row + row0 + i;
    if (grow >= n) continue;
    float o[8];
    #pragma unroll
    for (int j = 0; j < 8; ++j) o[j] = fmaxf(acc[i][j] + bias[col0 + j], 0.f);
    *(float4*)&C[(size_t)grow * BN + col0] = *(float4*)&o[0];
    *(float4*)&C[(size_t)grow * BN + col0 + 4] = *(float4*)&o[4];
  }
}

// ---------------- pooling: sorted batch_index => segmented mean, no atomics ----------------
__global__ __launch_bounds__(128) void pool_mean_kernel(
    const float* __restrict__ h, const int* __restrict__ batch,
    float* __restrict__ pooled, int n) {
  int b = blockIdx.x;
  // lower_bound(batch, b) and lower_bound(batch, b+1)
  int lo = 0, hi = n;
  while (lo < hi) { int mid = (lo + hi) >> 1; if (batch[mid] < b) lo = mid + 1; else hi = mid; }
  int s = lo;
  hi = n;
  while (lo < hi) { int mid = (lo + hi) >> 1; if (batch[mid] < b + 1) lo = mid + 1; else hi = mid; }
  int e = lo;
  int t = threadIdx.x;  // feature t of 128; coalesced 512B per node
  float acc = 0.f;
  for (int i = s; i < e; ++i) acc += h[(size_t)i * 128 + t];
  float c = fmaxf((float)(e - s), 1.0f);
  pooled[b * 128 + t] = acc / c;
}

// ---------------- per-graph MLP head ----------------
__global__ __launch_bounds__(128) void mlp_kernel(
    const float* __restrict__ pooled,
    const float* __restrict__ lW1, const float* __restrict__ lb1,
    const float* __restrict__ lW2, const float* __restrict__ lb2,
    const float* __restrict__ gamma, const float* __restrict__ beta,
    const float* __restrict__ rm, const float* __restrict__ rv,
    const float* __restrict__ oW, const float* __restrict__ ob,
    float* __restrict__ out, int B) {
  int b = blockIdx.x, t = threadIdx.x;
  __shared__ float p[128], h1[128];
  p[t] = pooled[b * 128 + t];
  __syncthreads();
  float a1 = lb1[t];
  for (int k = 0; k < 128; ++k) a1 += p[k] * lW1[k * 128 + t];
  h1[t] = a1;
  __syncthreads();
  if (t < 64) {
    float a2 = lb2[t];
    for (int k = 0; k < 128; ++k) a2 += h1[k] * lW2[k * 64 + t];
    a2 = (a2 - rm[t]) * gamma[t] * rsqrtf(rv[t] + 1e-5f) + beta[t];
    float hd = fmaxf(a2, 0.f);
    out[B + b * 64 + t] = hd;  // hidden, output 1
    float prod = hd * oW[t];
    #pragma unroll
    for (int off = 32; off > 0; off >>= 1) prod += __shfl_down(prod, off);
    if (t == 0) out[b] = prod + ob[0];  // out, output 0
  }
}

extern "C" void kernel_launch(void* const* d_in, const int* in_sizes, int n_in,
                              void* d_out, int out_size, void* d_ws, size_t ws_size,
                              hipStream_t stream) {
  const float* x = (const float*)d_in[0];
  const int* ei = (const int*)d_in[1];
  const int* batch = (const int*)d_in[2];
  const float* W1 = (const float*)d_in[3];  const float* b1 = (const float*)d_in[4];
  const float* W2 = (const float*)d_in[5];  const float* b2 = (const float*)d_in[6];
  const float* W3 = (const float*)d_in[7];  const float* b3 = (const float*)d_in[8];
  const float* W4 = (const float*)d_in[9];  const float* b4 = (const float*)d_in[10];
  const float* lW1 = (const float*)d_in[11]; const float* lb1 = (const float*)d_in[12];
  const float* lW2 = (const float*)d_in[13]; const float* lb2 = (const float*)d_in[14];
  const float* gamma = (const float*)d_in[15]; const float* beta = (const float*)d_in[16];
  const float* rm = (const float*)d_in[17]; const float* rv = (const float*)d_in[18];
  const float* oW = (const float*)d_in[19]; const float* ob = (const float*)d_in[20];

  const int n = in_sizes[2];
  const int E = in_sizes[1] / 2;
  const int B = out_size / 65;  // out_size = B + B*64
  const int* src = ei;
  const int* dst = ei + E;

  char* ws = (char*)d_ws;
  size_t off = 0;
  auto alloc = [&](size_t bytes) -> void* {
    void* p = ws + off;
    off += (bytes + 255) & ~(size_t)255;
    return p;
  };
  int* deg = (int*)alloc((size_t)n * 4);
  float* dinv = (float*)alloc((size_t)n * 4);
  int* rowptr = (int*)alloc((size_t)(n + 1) * 4);
  int* cursor = (int*)alloc((size_t)n * 4);
  int* bsum = (int*)alloc(256 * 4);
  int* bexcl = (int*)alloc(256 * 4);
  int* col = (int*)alloc((size_t)E * 4);
  float* wv = (float*)alloc((size_t)E * 4);
  float* agg = (float*)alloc((size_t)n * 128 * 4);
  float* hbuf = (float*)alloc((size_t)n * 128 * 4);
  float* pooled = (float*)alloc((size_t)B * 128 * 4);

  hipMemsetAsync(deg, 0, (size_t)n * 4, stream);
  hipMemsetAsync(cursor, 0, (size_t)n * 4, stream);

  const int nb = (n + 255) / 256;  // 196 blocks <= 256, fits single-block scan
  hist_kernel<<<(E + 255) / 256, 256, 0, stream>>>(dst, deg, E);
  dinv_kernel<<<nb, 256, 0, stream>>>(deg, dinv, n);
  partial_sum_kernel<<<nb, 256, 0, stream>>>(deg, bsum, n);
  scan_bsum_kernel<<<1, 256, 0, stream>>>(bsum, bexcl, nb, rowptr + n);
  rowptr_kernel<<<nb, 256, 0, stream>>>(deg, bexcl, rowptr, n);
  fill_kernel<<<(E + 255) / 256, 256, 0, stream>>>(src, dst, dinv, rowptr, cursor, col, wv, E);

  const int aggblocks = (n + 3) / 4;     // 4 waves (nodes) per block
  const int gemmblocks = (n + 63) / 64;  // 64 rows per block

  aggregate_kernel<64><<<aggblocks, 256, 0, stream>>>(x, rowptr, col, wv, dinv, agg, n);
  gemm_bias_relu_kernel<64><<<gemmblocks, 256, 0, stream>>>(agg, W1, b1, hbuf, n);
  aggregate_kernel<128><<<aggblocks, 256, 0, stream>>>(hbuf, rowptr, col, wv, dinv, agg, n);
  gemm_bias_relu_kernel<128><<<gemmblocks, 256, 0, stream>>>(agg, W2, b2, hbuf, n);
  aggregate_kernel<128><<<aggblocks, 256, 0, stream>>>(hbuf, rowptr, col, wv, dinv, agg, n);
  gemm_bias_relu_kernel<128><<<gemmblocks, 256, 0, stream>>>(agg, W3, b3, hbuf, n);
  aggregate_kernel<128><<<aggblocks, 256, 0, stream>>>(hbuf, rowptr, col, wv, dinv, agg, n);
  gemm_bias_relu_kernel<128><<<gemmblocks, 256, 0, stream>>>(agg, W4, b4, hbuf, n);

  pool_mean_kernel<<<B, 128, 0, stream>>>(hbuf, batch, pooled, n);
  mlp_kernel<<<B, 128, 0, stream>>>(pooled, lW1, lb1, lW2, lb2, gamma, beta, rm, rv, oW, ob,
                                    (float*)d_out, B);
}

// Round 5
// 460.583 us; speedup vs baseline: 1.3183x; 1.0958x over previous
//
#include <hip/hip_runtime.h>

// ---------------- CSR build ----------------
__global__ void hist_kernel(const int* __restrict__ dst, int* __restrict__ deg, int E) {
  int e = blockIdx.x * blockDim.x + threadIdx.x;
  if (e < E) atomicAdd(&deg[dst[e]], 1);
}

__global__ void dinv_kernel(const int* __restrict__ deg, float* __restrict__ dinv, int n) {
  int i = blockIdx.x * blockDim.x + threadIdx.x;
  if (i < n) dinv[i] = rsqrtf((float)(deg[i] + 1));  // +1 self loop
}

__global__ void partial_sum_kernel(const int* __restrict__ cnt, int* __restrict__ bsum, int n) {
  __shared__ int s[256];
  int i = blockIdx.x * 256 + threadIdx.x;
  s[threadIdx.x] = (i < n) ? cnt[i] : 0;
  __syncthreads();
  for (int off = 128; off > 0; off >>= 1) {
    if (threadIdx.x < off) s[threadIdx.x] += s[threadIdx.x + off];
    __syncthreads();
  }
  if (threadIdx.x == 0) bsum[blockIdx.x] = s[0];
}

__global__ void scan_bsum_kernel(const int* __restrict__ bsum, int* __restrict__ bexcl,
                                 int nb, int* __restrict__ rowptr_last) {
  __shared__ int s[256];
  int t = threadIdx.x;
  int v = (t < nb) ? bsum[t] : 0;
  s[t] = v;
  __syncthreads();
  for (int off = 1; off < 256; off <<= 1) {
    int add = (t >= off) ? s[t - off] : 0;
    __syncthreads();
    s[t] += add;
    __syncthreads();
  }
  if (t < nb) bexcl[t] = s[t] - v;
  if (t == 255) *rowptr_last = s[255];
}

__global__ void rowptr_kernel(const int* __restrict__ cnt, const int* __restrict__ bexcl,
                              int* __restrict__ rowptr, int n) {
  __shared__ int s[256];
  int i = blockIdx.x * 256 + threadIdx.x;
  int t = threadIdx.x;
  int v = (i < n) ? cnt[i] : 0;
  s[t] = v;
  __syncthreads();
  for (int off = 1; off < 256; off <<= 1) {
    int add = (t >= off) ? s[t - off] : 0;
    __syncthreads();
    s[t] += add;
    __syncthreads();
  }
  if (i < n) rowptr[i] = bexcl[blockIdx.x] + s[t] - v;
}

__global__ void fill_kernel(const int* __restrict__ src, const int* __restrict__ dst,
                            const float* __restrict__ dinv, const int* __restrict__ rowptr,
                            int* __restrict__ cursor, int* __restrict__ col,
                            float* __restrict__ wv, int E) {
  int e = blockIdx.x * blockDim.x + threadIdx.x;
  if (e >= E) return;
  int s = src[e], d = dst[e];
  int p = atomicAdd(&cursor[d], 1);
  int slot = rowptr[d] + p;
  col[slot] = s;
  wv[slot] = dinv[s] * dinv[d];
}

// ---------------- aggregation: agg[i] = dinv[i]^2*h[i] + sum_e wv*h[col] ----------------
// One wave per node. Edge loop unrolled x8 so 8 gather loads are in flight per wave
// (VGPR=12 rolled version was load->waitcnt->fma serialized => latency-bound, 66us).
template <int D>
__global__ __launch_bounds__(256) void aggregate_kernel(
    const float* __restrict__ h, const int* __restrict__ rowptr, const int* __restrict__ col,
    const float* __restrict__ wv, const float* __restrict__ dinv, float* __restrict__ out, int n) {
  int wid = (blockIdx.x * 256 + threadIdx.x) >> 6;  // one wave per node
  int lane = threadIdx.x & 63;
  if (wid >= n) return;
  float di = dinv[wid];
  float sl = di * di;
  int beg = rowptr[wid], end = rowptr[wid + 1];
  if constexpr (D == 64) {
    float acc = sl * h[(size_t)wid * 64 + lane];
    for (int base = beg; base < end; base += 64) {
      int kk = base + lane;
      int c = 0; float ww = 0.f;  // lanes past end carry c=0, ww=0 -> shfl tail is weight-0
      if (kk < end) { c = col[kk]; ww = wv[kk]; }
      int m = end - base; if (m > 64) m = 64;
      for (int t0 = 0; t0 < m; t0 += 8) {
        float v[8]; float ws[8];
        #pragma unroll
        for (int u = 0; u < 8; ++u) {
          int t = t0 + u;                  // t may exceed m on tail: weight 0, row-0 load (cached)
          int cs = __shfl(c, t);
          ws[u] = __shfl(ww, t);
          v[u] = h[(size_t)cs * 64 + lane];
        }
        #pragma unroll
        for (int u = 0; u < 8; ++u) acc += ws[u] * v[u];
      }
    }
    out[(size_t)wid * 64 + lane] = acc;
  } else {
    const float2* h2 = (const float2*)h;
    float2 hv = h2[(size_t)wid * 64 + lane];
    float ax = sl * hv.x, ay = sl * hv.y;
    for (int base = beg; base < end; base += 64) {
      int kk = base + lane;
      int c = 0; float ww = 0.f;
      if (kk < end) { c = col[kk]; ww = wv[kk]; }
      int m = end - base; if (m > 64) m = 64;
      for (int t0 = 0; t0 < m; t0 += 8) {
        float2 v[8]; float ws[8];
        #pragma unroll
        for (int u = 0; u < 8; ++u) {
          int t = t0 + u;
          int cs = __shfl(c, t);
          ws[u] = __shfl(ww, t);
          v[u] = h2[(size_t)cs * 64 + lane];
        }
        #pragma unroll
        for (int u = 0; u < 8; ++u) { ax += ws[u] * v[u].x; ay += ws[u] * v[u].y; }
      }
    }
    float2 o; o.x = ax; o.y = ay;
    ((float2*)out)[(size_t)wid * 64 + lane] = o;
  }
}

// ---------------- C = relu(A @ W + b), A[n,K], W[K,128] ----------------
template <int K>
__global__ __launch_bounds__(256) void gemm_bias_relu_kernel(
    const float* __restrict__ A, const float* __restrict__ W, const float* __restrict__ bias,
    float* __restrict__ C, int n) {
  constexpr int BM = 64, BN = 128, BK = 32;
  __shared__ float At[BK][BM + 4];  // transposed A tile
  __shared__ float Ws[BK][BN];
  const int tid = threadIdx.x;
  const int block_row = blockIdx.x * BM;
  const int tr = tid >> 4, tc = tid & 15;
  const int row0 = tr * 4, col0 = tc * 8;
  float acc[4][8] = {};
  for (int kb = 0; kb < K; kb += BK) {
    {  // A tile: 64x32, 8 floats/thread
      int r = tid >> 2;
      int k = (tid & 3) * 8;
      int grow = block_row + r;
      float4 v0 = {0, 0, 0, 0}, v1 = {0, 0, 0, 0};
      if (grow < n) {
        v0 = *(const float4*)&A[(size_t)grow * K + kb + k];
        v1 = *(const float4*)&A[(size_t)grow * K + kb + k + 4];
      }
      At[k + 0][r] = v0.x; At[k + 1][r] = v0.y; At[k + 2][r] = v0.z; At[k + 3][r] = v0.w;
      At[k + 4][r] = v1.x; At[k + 5][r] = v1.y; At[k + 6][r] = v1.z; At[k + 7][r] = v1.w;
    }
    #pragma unroll
    for (int t = 0; t < 4; ++t) {  // W tile: 32x128 = 1024 float4, 4/thread
      int idx4 = tid + t * 256;
      int k = idx4 >> 5;
      int c4 = idx4 & 31;
      *(float4*)&Ws[k][c4 * 4] = *(const float4*)&W[(size_t)(kb + k) * BN + c4 * 4];
    }
    __syncthreads();
    #pragma unroll
    for (int k = 0; k < BK; ++k) {
      float a[4], w[8];
      *(float4*)&a[0] = *(const float4*)&At[k][row0];
      *(float4*)&w[0] = *(const float4*)&Ws[k][col0];
      *(float4*)&w[4] = *(const float4*)&Ws[k][col0 + 4];
      #pragma unroll
      for (int i = 0; i < 4; ++i)
        #pragma unroll
        for (int j = 0; j < 8; ++j)
          acc[i][j] += a[i] * w[j];
    }
    __syncthreads();
  }
  #pragma unroll
  for (int i = 0; i < 4; ++i) {
    int grow = block_row + row0 + i;
    if (grow >= n) continue;
    float o[8];
    #pragma unroll
    for (int j = 0; j < 8; ++j) o[j] = fmaxf(acc[i][j] + bias[col0 + j], 0.f);
    *(float4*)&C[(size_t)grow * BN + col0] = *(float4*)&o[0];
    *(float4*)&C[(size_t)grow * BN + col0 + 4] = *(float4*)&o[4];
  }
}

// ---------------- pooling: sorted batch_index => segmented mean, no atomics ----------------
__global__ __launch_bounds__(128) void pool_mean_kernel(
    const float* __restrict__ h, const int* __restrict__ batch,
    float* __restrict__ pooled, int n) {
  int b = blockIdx.x;
  int lo = 0, hi = n;
  while (lo < hi) { int mid = (lo + hi) >> 1; if (batch[mid] < b) lo = mid + 1; else hi = mid; }
  int s = lo;
  hi = n;
  while (lo < hi) { int mid = (lo + hi) >> 1; if (batch[mid] < b + 1) lo = mid + 1; else hi = mid; }
  int e = lo;
  int t = threadIdx.x;  // feature t of 128; coalesced 512B per node
  float acc = 0.f;
  for (int i = s; i < e; ++i) acc += h[(size_t)i * 128 + t];
  float c = fmaxf((float)(e - s), 1.0f);
  pooled[b * 128 + t] = acc / c;
}

// ---------------- per-graph MLP head ----------------
__global__ __launch_bounds__(128) void mlp_kernel(
    const float* __restrict__ pooled,
    const float* __restrict__ lW1, const float* __restrict__ lb1,
    const float* __restrict__ lW2, const float* __restrict__ lb2,
    const float* __restrict__ gamma, const float* __restrict__ beta,
    const float* __restrict__ rm, const float* __restrict__ rv,
    const float* __restrict__ oW, const float* __restrict__ ob,
    float* __restrict__ out, int B) {
  int b = blockIdx.x, t = threadIdx.x;
  __shared__ float p[128], h1[128];
  p[t] = pooled[b * 128 + t];
  __syncthreads();
  float a1 = lb1[t];
  for (int k = 0; k < 128; ++k) a1 += p[k] * lW1[k * 128 + t];
  h1[t] = a1;
  __syncthreads();
  if (t < 64) {
    float a2 = lb2[t];
    for (int k = 0; k < 128; ++k) a2 += h1[k] * lW2[k * 64 + t];
    a2 = (a2 - rm[t]) * gamma[t] * rsqrtf(rv[t] + 1e-5f) + beta[t];
    float hd = fmaxf(a2, 0.f);
    out[B + b * 64 + t] = hd;  // hidden, output 1
    float prod = hd * oW[t];
    #pragma unroll
    for (int off = 32; off > 0; off >>= 1) prod += __shfl_down(prod, off);
    if (t == 0) out[b] = prod + ob[0];  // out, output 0
  }
}

extern "C" void kernel_launch(void* const* d_in, const int* in_sizes, int n_in,
                              void* d_out, int out_size, void* d_ws, size_t ws_size,
                              hipStream_t stream) {
  const float* x = (const float*)d_in[0];
  const int* ei = (const int*)d_in[1];
  const int* batch = (const int*)d_in[2];
  const float* W1 = (const float*)d_in[3];  const float* b1 = (const float*)d_in[4];
  const float* W2 = (const float*)d_in[5];  const float* b2 = (const float*)d_in[6];
  const float* W3 = (const float*)d_in[7];  const float* b3 = (const float*)d_in[8];
  const float* W4 = (const float*)d_in[9];  const float* b4 = (const float*)d_in[10];
  const float* lW1 = (const float*)d_in[11]; const float* lb1 = (const float*)d_in[12];
  const float* lW2 = (const float*)d_in[13]; const float* lb2 = (const float*)d_in[14];
  const float* gamma = (const float*)d_in[15]; const float* beta = (const float*)d_in[16];
  const float* rm = (const float*)d_in[17]; const float* rv = (const float*)d_in[18];
  const float* oW = (const float*)d_in[19]; const float* ob = (const float*)d_in[20];

  const int n = in_sizes[2];
  const int E = in_sizes[1] / 2;
  const int B = out_size / 65;  // out_size = B + B*64
  const int* src = ei;
  const int* dst = ei + E;

  char* ws = (char*)d_ws;
  size_t off = 0;
  auto alloc = [&](size_t bytes) -> void* {
    void* p = ws + off;
    off += (bytes + 255) & ~(size_t)255;
    return p;
  };
  int* deg = (int*)alloc((size_t)n * 4);
  float* dinv = (float*)alloc((size_t)n * 4);
  int* rowptr = (int*)alloc((size_t)(n + 1) * 4);
  int* cursor = (int*)alloc((size_t)n * 4);
  int* bsum = (int*)alloc(256 * 4);
  int* bexcl = (int*)alloc(256 * 4);
  int* col = (int*)alloc((size_t)E * 4);
  float* wv = (float*)alloc((size_t)E * 4);
  float* agg = (float*)alloc((size_t)n * 128 * 4);
  float* hbuf = (float*)alloc((size_t)n * 128 * 4);
  float* pooled = (float*)alloc((size_t)B * 128 * 4);

  hipMemsetAsync(deg, 0, (size_t)n * 4, stream);
  hipMemsetAsync(cursor, 0, (size_t)n * 4, stream);

  const int nb = (n + 255) / 256;  // 196 blocks <= 256, fits single-block scan
  hist_kernel<<<(E + 255) / 256, 256, 0, stream>>>(dst, deg, E);
  dinv_kernel<<<nb, 256, 0, stream>>>(deg, dinv, n);
  partial_sum_kernel<<<nb, 256, 0, stream>>>(deg, bsum, n);
  scan_bsum_kernel<<<1, 256, 0, stream>>>(bsum, bexcl, nb, rowptr + n);
  rowptr_kernel<<<nb, 256, 0, stream>>>(deg, bexcl, rowptr, n);
  fill_kernel<<<(E + 255) / 256, 256, 0, stream>>>(src, dst, dinv, rowptr, cursor, col, wv, E);

  const int aggblocks = (n + 3) / 4;     // 4 waves (nodes) per block
  const int gemmblocks = (n + 63) / 64;  // 64 rows per block

  aggregate_kernel<64><<<aggblocks, 256, 0, stream>>>(x, rowptr, col, wv, dinv, agg, n);
  gemm_bias_relu_kernel<64><<<gemmblocks, 256, 0, stream>>>(agg, W1, b1, hbuf, n);
  aggregate_kernel<128><<<aggblocks, 256, 0, stream>>>(hbuf, rowptr, col, wv, dinv, agg, n);
  gemm_bias_relu_kernel<128><<<gemmblocks, 256, 0, stream>>>(agg, W2, b2, hbuf, n);
  aggregate_kernel<128><<<aggblocks, 256, 0, stream>>>(hbuf, rowptr, col, wv, dinv, agg, n);
  gemm_bias_relu_kernel<128><<<gemmblocks, 256, 0, stream>>>(agg, W3, b3, hbuf, n);
  aggregate_kernel<128><<<aggblocks, 256, 0, stream>>>(hbuf, rowptr, col, wv, dinv, agg, n);
  gemm_bias_relu_kernel<128><<<gemmblocks, 256, 0, stream>>>(agg, W4, b4, hbuf, n);

  pool_mean_kernel<<<B, 128, 0, stream>>>(hbuf, batch, pooled, n);
  mlp_kernel<<<B, 128, 0, stream>>>(pooled, lW1, lb1, lW2, lb2, gamma, beta, rm, rv, oW, ob,
                                    (float*)d_out, B);
}

// Round 7
// 458.089 us; speedup vs baseline: 1.3255x; 1.0054x over previous
//
#include <hip/hip_runtime.h>

// ---------------- CSR build ----------------
__global__ void hist_kernel(const int* __restrict__ dst, int* __restrict__ deg, int E) {
  int e = blockIdx.x * blockDim.x + threadIdx.x;
  if (e < E) atomicAdd(&deg[dst[e]], 1);
}

__global__ void dinv_kernel(const int* __restrict__ deg, float* __restrict__ dinv, int n) {
  int i = blockIdx.x * blockDim.x + threadIdx.x;
  if (i < n) dinv[i] = rsqrtf((float)(deg[i] + 1));  // +1 self loop
}

__global__ void partial_sum_kernel(const int* __restrict__ cnt, int* __restrict__ bsum, int n) {
  __shared__ int s[256];
  int i = blockIdx.x * 256 + threadIdx.x;
  s[threadIdx.x] = (i < n) ? cnt[i] : 0;
  __syncthreads();
  for (int off = 128; off > 0; off >>= 1) {
    if (threadIdx.x < off) s[threadIdx.x] += s[threadIdx.x + off];
    __syncthreads();
  }
  if (threadIdx.x == 0) bsum[blockIdx.x] = s[0];
}

__global__ void scan_bsum_kernel(const int* __restrict__ bsum, int* __restrict__ bexcl,
                                 int nb, int* __restrict__ rowptr_last) {
  __shared__ int s[256];
  int t = threadIdx.x;
  int v = (t < nb) ? bsum[t] : 0;
  s[t] = v;
  __syncthreads();
  for (int off = 1; off < 256; off <<= 1) {
    int add = (t >= off) ? s[t - off] : 0;
    __syncthreads();
    s[t] += add;
    __syncthreads();
  }
  if (t < nb) bexcl[t] = s[t] - v;
  if (t == 255) *rowptr_last = s[255];
}

__global__ void rowptr_kernel(const int* __restrict__ cnt, const int* __restrict__ bexcl,
                              int* __restrict__ rowptr, int n) {
  __shared__ int s[256];
  int i = blockIdx.x * 256 + threadIdx.x;
  int t = threadIdx.x;
  int v = (i < n) ? cnt[i] : 0;
  s[t] = v;
  __syncthreads();
  for (int off = 1; off < 256; off <<= 1) {
    int add = (t >= off) ? s[t - off] : 0;
    __syncthreads();
    s[t] += add;
    __syncthreads();
  }
  if (i < n) rowptr[i] = bexcl[blockIdx.x] + s[t] - v;
}

// packed (col, wv) single 8B store: one random cache line per edge instead of two
__global__ void fill_kernel(const int* __restrict__ src, const int* __restrict__ dst,
                            const float* __restrict__ dinv, const int* __restrict__ rowptr,
                            int* __restrict__ cursor, int2* __restrict__ colwv, int E) {
  int e = blockIdx.x * blockDim.x + threadIdx.x;
  if (e >= E) return;
  int s = src[e], d = dst[e];
  int p = atomicAdd(&cursor[d], 1);
  int slot = rowptr[d] + p;
  int2 packed;
  packed.x = s;
  packed.y = __float_as_int(dinv[s] * dinv[d]);
  colwv[slot] = packed;
}

// ---------------- aggregation: agg[i] = dinv[i]^2*h[i] + sum_e wv*h[col] ----------------
// One wave per node; float4 gathers. D=128: 2 edges/instruction-group (32 lanes x 16B each);
// D=64: 4 edges/group (16 lanes x 16B). 8 float4 loads in flight per wave.
template <int D>
__global__ __launch_bounds__(256) void aggregate_kernel(
    const float* __restrict__ h, const int* __restrict__ rowptr,
    const int2* __restrict__ colwv, const float* __restrict__ dinv,
    float* __restrict__ out, int n) {
  int wid = (blockIdx.x * 256 + threadIdx.x) >> 6;  // one wave per node
  int lane = threadIdx.x & 63;
  if (wid >= n) return;
  float di = dinv[wid];
  float sl = di * di;
  int beg = rowptr[wid], end = rowptr[wid + 1];
  const float4* h4 = (const float4*)h;
  float4 acc = {0.f, 0.f, 0.f, 0.f};
  if constexpr (D == 128) {
    const int half = lane >> 5;  // which edge of a pair
    const int l32 = lane & 31;   // feature quad (128 = 32 x float4)
    for (int base = beg; base < end; base += 64) {
      int kk = base + lane;
      int c = 0; float ww = 0.f;  // lanes past end: weight 0 -> row-0 load harmless
      if (kk < end) { int2 e = colwv[kk]; c = e.x; ww = __int_as_float(e.y); }
      int m = end - base; if (m > 64) m = 64;
      for (int t0 = 0; t0 < m; t0 += 16) {  // 16 edges per batch (8 groups x 2)
        float4 v[8]; float ws[8];
        #pragma unroll
        for (int u = 0; u < 8; ++u) {
          int t = t0 + 2 * u + half;        // <= 63 always
          int cs = __shfl(c, t);
          ws[u] = __shfl(ww, t);
          v[u] = h4[(size_t)cs * 32 + l32];
        }
        #pragma unroll
        for (int u = 0; u < 8; ++u) {
          acc.x += ws[u] * v[u].x; acc.y += ws[u] * v[u].y;
          acc.z += ws[u] * v[u].z; acc.w += ws[u] * v[u].w;
        }
      }
    }
    acc.x += __shfl_xor(acc.x, 32); acc.y += __shfl_xor(acc.y, 32);
    acc.z += __shfl_xor(acc.z, 32); acc.w += __shfl_xor(acc.w, 32);
    if (half == 0) {
      float4 hv = h4[(size_t)wid * 32 + l32];
      acc.x += sl * hv.x; acc.y += sl * hv.y; acc.z += sl * hv.z; acc.w += sl * hv.w;
      ((float4*)out)[(size_t)wid * 32 + l32] = acc;
    }
  } else {  // D == 64
    const int q = lane >> 4;     // which edge of a quartet
    const int l16 = lane & 15;   // feature quad (64 = 16 x float4)
    for (int base = beg; base < end; base += 64) {
      int kk = base + lane;
      int c = 0; float ww = 0.f;
      if (kk < end) { int2 e = colwv[kk]; c = e.x; ww = __int_as_float(e.y); }
      int m = end - base; if (m > 64) m = 64;
      for (int t0 = 0; t0 < m; t0 += 32) {  // 32 edges per batch (8 groups x 4)
        float4 v[8]; float ws[8];
        #pragma unroll
        for (int u = 0; u < 8; ++u) {
          int t = t0 + 4 * u + q;           // <= 63 always
          int cs = __shfl(c, t);
          ws[u] = __shfl(ww, t);
          v[u] = h4[(size_t)cs * 16 + l16];
        }
        #pragma unroll
        for (int u = 0; u < 8; ++u) {
          acc.x += ws[u] * v[u].x; acc.y += ws[u] * v[u].y;
          acc.z += ws[u] * v[u].z; acc.w += ws[u] * v[u].w;
        }
      }
    }
    acc.x += __shfl_xor(acc.x, 16); acc.y += __shfl_xor(acc.y, 16);
    acc.z += __shfl_xor(acc.z, 16); acc.w += __shfl_xor(acc.w, 16);
    acc.x += __shfl_xor(acc.x, 32); acc.y += __shfl_xor(acc.y, 32);
    acc.z += __shfl_xor(acc.z, 32); acc.w += __shfl_xor(acc.w, 32);
    if (lane < 16) {
      float4 hv = h4[(size_t)wid * 16 + l16];
      acc.x += sl * hv.x; acc.y += sl * hv.y; acc.z += sl * hv.z; acc.w += sl * hv.w;
      ((float4*)out)[(size_t)wid * 16 + l16] = acc;
    }
  }
}

// ---------------- C = relu(A @ W + b), A[n,K], W[K,128] ----------------
template <int K>
__global__ __launch_bounds__(256) void gemm_bias_relu_kernel(
    const float* __restrict__ A, const float* __restrict__ W, const float* __restrict__ bias,
    float* __restrict__ C, int n) {
  constexpr int BM = 64, BN = 128, BK = 32;
  __shared__ float At[BK][BM + 4];  // transposed A tile
  __shared__ float Ws[BK][BN];
  const int tid = threadIdx.x;
  const int block_row = blockIdx.x * BM;
  const int tr = tid >> 4, tc = tid & 15;
  const int row0 = tr * 4, col0 = tc * 8;
  float acc[4][8] = {};
  for (int kb = 0; kb < K; kb += BK) {
    {  // A tile: 64x32, 8 floats/thread
      int r = tid >> 2;
      int k = (tid & 3) * 8;
      int grow = block_row + r;
      float4 v0 = {0, 0, 0, 0}, v1 = {0, 0, 0, 0};
      if (grow < n) {
        v0 = *(const float4*)&A[(size_t)grow * K + kb + k];
        v1 = *(const float4*)&A[(size_t)grow * K + kb + k + 4];
      }
      At[k + 0][r] = v0.x; At[k + 1][r] = v0.y; At[k + 2][r] = v0.z; At[k + 3][r] = v0.w;
      At[k + 4][r] = v1.x; At[k + 5][r] = v1.y; At[k + 6][r] = v1.z; At[k + 7][r] = v1.w;
    }
    #pragma unroll
    for (int t = 0; t < 4; ++t) {  // W tile: 32x128 = 1024 float4, 4/thread
      int idx4 = tid + t * 256;
      int k = idx4 >> 5;
      int c4 = idx4 & 31;
      *(float4*)&Ws[k][c4 * 4] = *(const float4*)&W[(size_t)(kb + k) * BN + c4 * 4];
    }
    __syncthreads();
    #pragma unroll
    for (int k = 0; k < BK; ++k) {
      float a[4], w[8];
      *(float4*)&a[0] = *(const float4*)&At[k][row0];
      *(float4*)&w[0] = *(const float4*)&Ws[k][col0];
      *(float4*)&w[4] = *(const float4*)&Ws[k][col0 + 4];
      #pragma unroll
      for (int i = 0; i < 4; ++i)
        #pragma unroll
        for (int j = 0; j < 8; ++j)
          acc[i][j] += a[i] * w[j];
    }
    __syncthreads();
  }
  #pragma unroll
  for (int i = 0; i < 4; ++i) {
    int grow = block_row + row0 + i;
    if (grow >= n) continue;
    float o[8];
    #pragma unroll
    for (int j = 0; j < 8; ++j) o[j] = fmaxf(acc[i][j] + bias[col0 + j], 0.f);
    *(float4*)&C[(size_t)grow * BN + col0] = *(float4*)&o[0];
    *(float4*)&C[(size_t)grow * BN + col0 + 4] = *(float4*)&o[4];
  }
}

// ---------------- pooling: sorted batch_index => segmented mean, no atomics ----------------
__global__ __launch_bounds__(128) void pool_mean_kernel(
    const float* __restrict__ h, const int* __restrict__ batch,
    float* __restrict__ pooled, int n) {
  int b = blockIdx.x;
  int lo = 0, hi = n;
  while (lo < hi) { int mid = (lo + hi) >> 1; if (batch[mid] < b) lo = mid + 1; else hi = mid; }
  int s = lo;
  hi = n;
  while (lo < hi) { int mid = (lo + hi) >> 1; if (batch[mid] < b + 1) lo = mid + 1; else hi = mid; }
  int e = lo;
  int t = threadIdx.x;  // feature t of 128; coalesced 512B per node
  float acc = 0.f;
  for (int i = s; i < e; ++i) acc += h[(size_t)i * 128 + t];
  float c = fmaxf((float)(e - s), 1.0f);
  pooled[b * 128 + t] = acc / c;
}

// ---------------- per-graph MLP head ----------------
__global__ __launch_bounds__(128) void mlp_kernel(
    const float* __restrict__ pooled,
    const float* __restrict__ lW1, const float* __restrict__ lb1,
    const float* __restrict__ lW2, const float* __restrict__ lb2,
    const float* __restrict__ gamma, const float* __restrict__ beta,
    const float* __restrict__ rm, const float* __restrict__ rv,
    const float* __restrict__ oW, const float* __restrict__ ob,
    float* __restrict__ out, int B) {
  int b = blockIdx.x, t = threadIdx.x;
  __shared__ float p[128], h1[128];
  p[t] = pooled[b * 128 + t];
  __syncthreads();
  float a1 = lb1[t];
  for (int k = 0; k < 128; ++k) a1 += p[k] * lW1[k * 128 + t];
  h1[t] = a1;
  __syncthreads();
  if (t < 64) {
    float a2 = lb2[t];
    for (int k = 0; k < 128; ++k) a2 += h1[k] * lW2[k * 64 + t];
    a2 = (a2 - rm[t]) * gamma[t] * rsqrtf(rv[t] + 1e-5f) + beta[t];
    float hd = fmaxf(a2, 0.f);
    out[B + b * 64 + t] = hd;  // hidden, output 1
    float prod = hd * oW[t];
    #pragma unroll
    for (int off = 32; off > 0; off >>= 1) prod += __shfl_down(prod, off);
    if (t == 0) out[b] = prod + ob[0];  // out, output 0
  }
}

extern "C" void kernel_launch(void* const* d_in, const int* in_sizes, int n_in,
                              void* d_out, int out_size, void* d_ws, size_t ws_size,
                              hipStream_t stream) {
  const float* x = (const float*)d_in[0];
  const int* ei = (const int*)d_in[1];
  const int* batch = (const int*)d_in[2];
  const float* W1 = (const float*)d_in[3];  const float* b1 = (const float*)d_in[4];
  const float* W2 = (const float*)d_in[5];  const float* b2 = (const float*)d_in[6];
  const float* W3 = (const float*)d_in[7];  const float* b3 = (const float*)d_in[8];
  const float* W4 = (const float*)d_in[9];  const float* b4 = (const float*)d_in[10];
  const float* lW1 = (const float*)d_in[11]; const float* lb1 = (const float*)d_in[12];
  const float* lW2 = (const float*)d_in[13]; const float* lb2 = (const float*)d_in[14];
  const float* gamma = (const float*)d_in[15]; const float* beta = (const float*)d_in[16];
  const float* rm = (const float*)d_in[17]; const float* rv = (const float*)d_in[18];
  const float* oW = (const float*)d_in[19]; const float* ob = (const float*)d_in[20];

  const int n = in_sizes[2];
  const int E = in_sizes[1] / 2;
  const int B = out_size / 65;  // out_size = B + B*64
  const int* src = ei;
  const int* dst = ei + E;

  char* ws = (char*)d_ws;
  size_t off = 0;
  auto alloc = [&](size_t bytes) -> void* {
    void* p = ws + off;
    off += (bytes + 255) & ~(size_t)255;
    return p;
  };
  int* deg = (int*)alloc((size_t)n * 4);
  float* dinv = (float*)alloc((size_t)n * 4);
  int* rowptr = (int*)alloc((size_t)(n + 1) * 4);
  int* cursor = (int*)alloc((size_t)n * 4);
  int* bsum = (int*)alloc(256 * 4);
  int* bexcl = (int*)alloc(256 * 4);
  int2* colwv = (int2*)alloc((size_t)E * 8);
  float* agg = (float*)alloc((size_t)n * 128 * 4);
  float* hbuf = (float*)alloc((size_t)n * 128 * 4);
  float* pooled = (float*)alloc((size_t)B * 128 * 4);

  hipMemsetAsync(deg, 0, (size_t)n * 4, stream);
  hipMemsetAsync(cursor, 0, (size_t)n * 4, stream);

  const int nb = (n + 255) / 256;  // 196 blocks <= 256, fits single-block scan
  hist_kernel<<<(E + 255) / 256, 256, 0, stream>>>(dst, deg, E);
  dinv_kernel<<<nb, 256, 0, stream>>>(deg, dinv, n);
  partial_sum_kernel<<<nb, 256, 0, stream>>>(deg, bsum, n);
  scan_bsum_kernel<<<1, 256, 0, stream>>>(bsum, bexcl, nb, rowptr + n);
  rowptr_kernel<<<nb, 256, 0, stream>>>(deg, bexcl, rowptr, n);
  fill_kernel<<<(E + 255) / 256, 256, 0, stream>>>(src, dst, dinv, rowptr, cursor, colwv, E);

  const int aggblocks = (n + 3) / 4;     // 4 waves (nodes) per block
  const int gemmblocks = (n + 63) / 64;  // 64 rows per block

  aggregate_kernel<64><<<aggblocks, 256, 0, stream>>>(x, rowptr, colwv, dinv, agg, n);
  gemm_bias_relu_kernel<64><<<gemmblocks, 256, 0, stream>>>(agg, W1, b1, hbuf, n);
  aggregate_kernel<128><<<aggblocks, 256, 0, stream>>>(hbuf, rowptr, colwv, dinv, agg, n);
  gemm_bias_relu_kernel<128><<<gemmblocks, 256, 0, stream>>>(agg, W2, b2, hbuf, n);
  aggregate_kernel<128><<<aggblocks, 256, 0, stream>>>(hbuf, rowptr, colwv, dinv, agg, n);
  gemm_bias_relu_kernel<128><<<gemmblocks, 256, 0, stream>>>(agg, W3, b3, hbuf, n);
  aggregate_kernel<128><<<aggblocks, 256, 0, stream>>>(hbuf, rowptr, colwv, dinv, agg, n);
  gemm_bias_relu_kernel<128><<<gemmblocks, 256, 0, stream>>>(agg, W4, b4, hbuf, n);

  pool_mean_kernel<<<B, 128, 0, stream>>>(hbuf, batch, pooled, n);
  mlp_kernel<<<B, 128, 0, stream>>>(pooled, lW1, lb1, lW2, lb2, gamma, beta, rm, rv, oW, ob,
                                    (float*)d_out, B);
}

// Round 8
// 376.705 us; speedup vs baseline: 1.6119x; 1.2160x over previous
//
#include <hip/hip_runtime.h>
#include <hip/hip_fp16.h>

struct alignas(8) half4v { __half2 a, b; };  // 4 halves, 8B

// ---------------- CSR build ----------------
__global__ void hist_kernel(const int* __restrict__ dst, int* __restrict__ deg, int E) {
  int e = blockIdx.x * blockDim.x + threadIdx.x;
  if (e < E) atomicAdd(&deg[dst[e]], 1);
}

__global__ void dinv_kernel(const int* __restrict__ deg, float* __restrict__ dinv, int n) {
  int i = blockIdx.x * blockDim.x + threadIdx.x;
  if (i < n) dinv[i] = rsqrtf((float)(deg[i] + 1));  // +1 self loop
}

__global__ void partial_sum_kernel(const int* __restrict__ cnt, int* __restrict__ bsum, int n) {
  __shared__ int s[256];
  int i = blockIdx.x * 256 + threadIdx.x;
  s[threadIdx.x] = (i < n) ? cnt[i] : 0;
  __syncthreads();
  for (int off = 128; off > 0; off >>= 1) {
    if (threadIdx.x < off) s[threadIdx.x] += s[threadIdx.x + off];
    __syncthreads();
  }
  if (threadIdx.x == 0) bsum[blockIdx.x] = s[0];
}

__global__ void scan_bsum_kernel(const int* __restrict__ bsum, int* __restrict__ bexcl,
                                 int nb, int* __restrict__ rowptr_last) {
  __shared__ int s[256];
  int t = threadIdx.x;
  int v = (t < nb) ? bsum[t] : 0;
  s[t] = v;
  __syncthreads();
  for (int off = 1; off < 256; off <<= 1) {
    int add = (t >= off) ? s[t - off] : 0;
    __syncthreads();
    s[t] += add;
    __syncthreads();
  }
  if (t < nb) bexcl[t] = s[t] - v;
  if (t == 255) *rowptr_last = s[255];
}

__global__ void rowptr_kernel(const int* __restrict__ cnt, const int* __restrict__ bexcl,
                              int* __restrict__ rowptr, int n) {
  __shared__ int s[256];
  int i = blockIdx.x * 256 + threadIdx.x;
  int t = threadIdx.x;
  int v = (i < n) ? cnt[i] : 0;
  s[t] = v;
  __syncthreads();
  for (int off = 1; off < 256; off <<= 1) {
    int add = (t >= off) ? s[t - off] : 0;
    __syncthreads();
    s[t] += add;
    __syncthreads();
  }
  if (i < n) rowptr[i] = bexcl[blockIdx.x] + s[t] - v;
}

// packed (col, wv) single 8B store: one random cache line per edge
__global__ void fill_kernel(const int* __restrict__ src, const int* __restrict__ dst,
                            const float* __restrict__ dinv, const int* __restrict__ rowptr,
                            int* __restrict__ cursor, int2* __restrict__ colwv, int E) {
  int e = blockIdx.x * blockDim.x + threadIdx.x;
  if (e >= E) return;
  int s = src[e], d = dst[e];
  int p = atomicAdd(&cursor[d], 1);
  int slot = rowptr[d] + p;
  int2 packed;
  packed.x = s;
  packed.y = __float_as_int(dinv[s] * dinv[d]);
  colwv[slot] = packed;
}

// ---------------- layer-1 aggregation (fp32 x, D=64) ----------------
__global__ __launch_bounds__(256) void aggregate64_kernel(
    const float* __restrict__ h, const int* __restrict__ rowptr,
    const int2* __restrict__ colwv, const float* __restrict__ dinv,
    float* __restrict__ out, int n) {
  int wid = (blockIdx.x * 256 + threadIdx.x) >> 6;  // one wave per node
  int lane = threadIdx.x & 63;
  if (wid >= n) return;
  float di = dinv[wid];
  float sl = di * di;
  int beg = rowptr[wid], end = rowptr[wid + 1];
  const float4* h4 = (const float4*)h;
  float4 acc = {0.f, 0.f, 0.f, 0.f};
  const int q = lane >> 4;     // which edge of a quartet
  const int l16 = lane & 15;   // feature quad (64 = 16 x float4)
  for (int base = beg; base < end; base += 64) {
    int kk = base + lane;
    int c = 0; float ww = 0.f;  // tail lanes: weight 0 -> row-0 load harmless
    if (kk < end) { int2 e = colwv[kk]; c = e.x; ww = __int_as_float(e.y); }
    int m = end - base; if (m > 64) m = 64;
    for (int t0 = 0; t0 < m; t0 += 32) {
      float4 v[8]; float ws[8];
      #pragma unroll
      for (int u = 0; u < 8; ++u) {
        int t = t0 + 4 * u + q;
        int cs = __shfl(c, t);
        ws[u] = __shfl(ww, t);
        v[u] = h4[(size_t)cs * 16 + l16];
      }
      #pragma unroll
      for (int u = 0; u < 8; ++u) {
        acc.x += ws[u] * v[u].x; acc.y += ws[u] * v[u].y;
        acc.z += ws[u] * v[u].z; acc.w += ws[u] * v[u].w;
      }
    }
  }
  acc.x += __shfl_xor(acc.x, 16); acc.y += __shfl_xor(acc.y, 16);
  acc.z += __shfl_xor(acc.z, 16); acc.w += __shfl_xor(acc.w, 16);
  acc.x += __shfl_xor(acc.x, 32); acc.y += __shfl_xor(acc.y, 32);
  acc.z += __shfl_xor(acc.z, 32); acc.w += __shfl_xor(acc.w, 32);
  if (lane < 16) {
    float4 hv = h4[(size_t)wid * 16 + l16];
    acc.x += sl * hv.x; acc.y += sl * hv.y; acc.z += sl * hv.z; acc.w += sl * hv.w;
    ((float4*)out)[(size_t)wid * 16 + l16] = acc;
  }
}

// ---------------- layers 2-4 aggregation (fp16 hbuf, D=128) ----------------
// Gather bytes halved vs fp32: row = 256B. 32 lanes x 8B per edge, 2 edges/group, 8 in flight.
__global__ __launch_bounds__(256) void aggregate128h_kernel(
    const __half* __restrict__ h, const int* __restrict__ rowptr,
    const int2* __restrict__ colwv, const float* __restrict__ dinv,
    float* __restrict__ out, int n) {
  int wid = (blockIdx.x * 256 + threadIdx.x) >> 6;
  int lane = threadIdx.x & 63;
  if (wid >= n) return;
  float di = dinv[wid];
  float sl = di * di;
  int beg = rowptr[wid], end = rowptr[wid + 1];
  const half4v* h4 = (const half4v*)h;  // 32 half4v per row
  float4 acc = {0.f, 0.f, 0.f, 0.f};
  const int hf = lane >> 5;
  const int l32 = lane & 31;
  for (int base = beg; base < end; base += 64) {
    int kk = base + lane;
    int c = 0; float ww = 0.f;
    if (kk < end) { int2 e = colwv[kk]; c = e.x; ww = __int_as_float(e.y); }
    int m = end - base; if (m > 64) m = 64;
    for (int t0 = 0; t0 < m; t0 += 16) {
      half4v v[8]; float ws[8];
      #pragma unroll
      for (int u = 0; u < 8; ++u) {
        int t = t0 + 2 * u + hf;
        int cs = __shfl(c, t);
        ws[u] = __shfl(ww, t);
        v[u] = h4[(size_t)cs * 32 + l32];
      }
      #pragma unroll
      for (int u = 0; u < 8; ++u) {
        float2 fa = __half22float2(v[u].a);
        float2 fb = __half22float2(v[u].b);
        acc.x += ws[u] * fa.x; acc.y += ws[u] * fa.y;
        acc.z += ws[u] * fb.x; acc.w += ws[u] * fb.y;
      }
    }
  }
  acc.x += __shfl_xor(acc.x, 32); acc.y += __shfl_xor(acc.y, 32);
  acc.z += __shfl_xor(acc.z, 32); acc.w += __shfl_xor(acc.w, 32);
  if (hf == 0) {
    half4v hv = h4[(size_t)wid * 32 + l32];
    float2 fa = __half22float2(hv.a);
    float2 fb = __half22float2(hv.b);
    acc.x += sl * fa.x; acc.y += sl * fa.y; acc.z += sl * fb.x; acc.w += sl * fb.y;
    ((float4*)out)[(size_t)wid * 32 + l32] = acc;
  }
}

// ---------------- C = relu(A @ W + b) -> fp16, A[n,K] fp32, W[K,128] ----------------
template <int K>
__global__ __launch_bounds__(256) void gemm_bias_relu_kernel(
    const float* __restrict__ A, const float* __restrict__ W, const float* __restrict__ bias,
    __half* __restrict__ C, int n) {
  constexpr int BM = 64, BN = 128, BK = 32;
  __shared__ float At[BK][BM + 4];  // transposed A tile
  __shared__ float Ws[BK][BN];
  const int tid = threadIdx.x;
  const int block_row = blockIdx.x * BM;
  const int tr = tid >> 4, tc = tid & 15;
  const int row0 = tr * 4, col0 = tc * 8;
  float acc[4][8] = {};
  for (int kb = 0; kb < K; kb += BK) {
    {  // A tile: 64x32, 8 floats/thread
      int r = tid >> 2;
      int k = (tid & 3) * 8;
      int grow = block_row + r;
      float4 v0 = {0, 0, 0, 0}, v1 = {0, 0, 0, 0};
      if (grow < n) {
        v0 = *(const float4*)&A[(size_t)grow * K + kb + k];
        v1 = *(const float4*)&A[(size_t)grow * K + kb + k + 4];
      }
      At[k + 0][r] = v0.x; At[k + 1][r] = v0.y; At[k + 2][r] = v0.z; At[k + 3][r] = v0.w;
      At[k + 4][r] = v1.x; At[k + 5][r] = v1.y; At[k + 6][r] = v1.z; At[k + 7][r] = v1.w;
    }
    #pragma unroll
    for (int t = 0; t < 4; ++t) {  // W tile: 32x128 = 1024 float4, 4/thread
      int idx4 = tid + t * 256;
      int k = idx4 >> 5;
      int c4 = idx4 & 31;
      *(float4*)&Ws[k][c4 * 4] = *(const float4*)&W[(size_t)(kb + k) * BN + c4 * 4];
    }
    __syncthreads();
    #pragma unroll
    for (int k = 0; k < BK; ++k) {
      float a[4], w[8];
      *(float4*)&a[0] = *(const float4*)&At[k][row0];
      *(float4*)&w[0] = *(const float4*)&Ws[k][col0];
      *(float4*)&w[4] = *(const float4*)&Ws[k][col0 + 4];
      #pragma unroll
      for (int i = 0; i < 4; ++i)
        #pragma unroll
        for (int j = 0; j < 8; ++j)
          acc[i][j] += a[i] * w[j];
    }
    __syncthreads();
  }
  #pragma unroll
  for (int i = 0; i < 4; ++i) {
    int grow = block_row + row0 + i;
    if (grow >= n) continue;
    alignas(16) __half o[8];
    #pragma unroll
    for (int j = 0; j < 8; ++j) o[j] = __float2half(fmaxf(acc[i][j] + bias[col0 + j], 0.f));
    *(uint4*)&C[(size_t)grow * BN + col0] = *(uint4*)&o[0];  // 8 halves = 16B
  }
}

// ---------------- pooling: sorted batch_index => segmented mean over fp16 h ----------------
__global__ __launch_bounds__(128) void pool_mean_kernel(
    const __half* __restrict__ h, const int* __restrict__ batch,
    float* __restrict__ pooled, int n) {
  int b = blockIdx.x;
  int lo = 0, hi = n;
  while (lo < hi) { int mid = (lo + hi) >> 1; if (batch[mid] < b) lo = mid + 1; else hi = mid; }
  int s = lo;
  hi = n;
  while (lo < hi) { int mid = (lo + hi) >> 1; if (batch[mid] < b + 1) lo = mid + 1; else hi = mid; }
  int e = lo;
  int t = threadIdx.x;  // feature t of 128; 256B contiguous per node
  float acc = 0.f;
  for (int i = s; i < e; ++i) acc += __half2float(h[(size_t)i * 128 + t]);
  float c = fmaxf((float)(e - s), 1.0f);
  pooled[b * 128 + t] = acc / c;
}

// ---------------- per-graph MLP head ----------------
__global__ __launch_bounds__(128) void mlp_kernel(
    const float* __restrict__ pooled,
    const float* __restrict__ lW1, const float* __restrict__ lb1,
    const float* __restrict__ lW2, const float* __restrict__ lb2,
    const float* __restrict__ gamma, const float* __restrict__ beta,
    const float* __restrict__ rm, const float* __restrict__ rv,
    const float* __restrict__ oW, const float* __restrict__ ob,
    float* __restrict__ out, int B) {
  int b = blockIdx.x, t = threadIdx.x;
  __shared__ float p[128], h1[128];
  p[t] = pooled[b * 128 + t];
  __syncthreads();
  float a1 = lb1[t];
  for (int k = 0; k < 128; ++k) a1 += p[k] * lW1[k * 128 + t];
  h1[t] = a1;
  __syncthreads();
  if (t < 64) {
    float a2 = lb2[t];
    for (int k = 0; k < 128; ++k) a2 += h1[k] * lW2[k * 64 + t];
    a2 = (a2 - rm[t]) * gamma[t] * rsqrtf(rv[t] + 1e-5f) + beta[t];
    float hd = fmaxf(a2, 0.f);
    out[B + b * 64 + t] = hd;  // hidden, output 1
    float prod = hd * oW[t];
    #pragma unroll
    for (int off = 32; off > 0; off >>= 1) prod += __shfl_down(prod, off);
    if (t == 0) out[b] = prod + ob[0];  // out, output 0
  }
}

extern "C" void kernel_launch(void* const* d_in, const int* in_sizes, int n_in,
                              void* d_out, int out_size, void* d_ws, size_t ws_size,
                              hipStream_t stream) {
  const float* x = (const float*)d_in[0];
  const int* ei = (const int*)d_in[1];
  const int* batch = (const int*)d_in[2];
  const float* W1 = (const float*)d_in[3];  const float* b1 = (const float*)d_in[4];
  const float* W2 = (const float*)d_in[5];  const float* b2 = (const float*)d_in[6];
  const float* W3 = (const float*)d_in[7];  const float* b3 = (const float*)d_in[8];
  const float* W4 = (const float*)d_in[9];  const float* b4 = (const float*)d_in[10];
  const float* lW1 = (const float*)d_in[11]; const float* lb1 = (const float*)d_in[12];
  const float* lW2 = (const float*)d_in[13]; const float* lb2 = (const float*)d_in[14];
  const float* gamma = (const float*)d_in[15]; const float* beta = (const float*)d_in[16];
  const float* rm = (const float*)d_in[17]; const float* rv = (const float*)d_in[18];
  const float* oW = (const float*)d_in[19]; const float* ob = (const float*)d_in[20];

  const int n = in_sizes[2];
  const int E = in_sizes[1] / 2;
  const int B = out_size / 65;  // out_size = B + B*64
  const int* src = ei;
  const int* dst = ei + E;

  char* ws = (char*)d_ws;
  size_t off = 0;
  auto alloc = [&](size_t bytes) -> void* {
    void* p = ws + off;
    off += (bytes + 255) & ~(size_t)255;
    return p;
  };
  int* deg = (int*)alloc((size_t)n * 4);
  float* dinv = (float*)alloc((size_t)n * 4);
  int* rowptr = (int*)alloc((size_t)(n + 1) * 4);
  int* cursor = (int*)alloc((size_t)n * 4);
  int* bsum = (int*)alloc(256 * 4);
  int* bexcl = (int*)alloc(256 * 4);
  int2* colwv = (int2*)alloc((size_t)E * 8);
  float* agg = (float*)alloc((size_t)n * 128 * 4);
  __half* hbuf = (__half*)alloc((size_t)n * 128 * 2);
  float* pooled = (float*)alloc((size_t)B * 128 * 4);

  hipMemsetAsync(deg, 0, (size_t)n * 4, stream);
  hipMemsetAsync(cursor, 0, (size_t)n * 4, stream);

  const int nb = (n + 255) / 256;  // 196 blocks <= 256, fits single-block scan
  hist_kernel<<<(E + 255) / 256, 256, 0, stream>>>(dst, deg, E);
  dinv_kernel<<<nb, 256, 0, stream>>>(deg, dinv, n);
  partial_sum_kernel<<<nb, 256, 0, stream>>>(deg, bsum, n);
  scan_bsum_kernel<<<1, 256, 0, stream>>>(bsum, bexcl, nb, rowptr + n);
  rowptr_kernel<<<nb, 256, 0, stream>>>(deg, bexcl, rowptr, n);
  fill_kernel<<<(E + 255) / 256, 256, 0, stream>>>(src, dst, dinv, rowptr, cursor, colwv, E);

  const int aggblocks = (n + 3) / 4;     // 4 waves (nodes) per block
  const int gemmblocks = (n + 63) / 64;  // 64 rows per block

  aggregate64_kernel<<<aggblocks, 256, 0, stream>>>(x, rowptr, colwv, dinv, agg, n);
  gemm_bias_relu_kernel<64><<<gemmblocks, 256, 0, stream>>>(agg, W1, b1, hbuf, n);
  aggregate128h_kernel<<<aggblocks, 256, 0, stream>>>(hbuf, rowptr, colwv, dinv, agg, n);
  gemm_bias_relu_kernel<128><<<gemmblocks, 256, 0, stream>>>(agg, W2, b2, hbuf, n);
  aggregate128h_kernel<<<aggblocks, 256, 0, stream>>>(hbuf, rowptr, colwv, dinv, agg, n);
  gemm_bias_relu_kernel<128><<<gemmblocks, 256, 0, stream>>>(agg, W3, b3, hbuf, n);
  aggregate128h_kernel<<<aggblocks, 256, 0, stream>>>(hbuf, rowptr, colwv, dinv, agg, n);
  gemm_bias_relu_kernel<128><<<gemmblocks, 256, 0, stream>>>(agg, W4, b4, hbuf, n);

  pool_mean_kernel<<<B, 128, 0, stream>>>(hbuf, batch, pooled, n);
  mlp_kernel<<<B, 128, 0, stream>>>(pooled, lW1, lb1, lW2, lb2, gamma, beta, rm, rv, oW, ob,
                                    (float*)d_out, B);
}

// Round 12
// 349.958 us; speedup vs baseline: 1.7351x; 1.0764x over previous
//
#include <hip/hip_runtime.h>
#include <hip/hip_fp16.h>

struct alignas(8) half4v { __half2 a, b; };  // 4 halves, 8B

// ---------------- CSR build ----------------
// hist also records each edge's arrival order within its dst row -> fill needs no cursor atomic
__global__ void hist_kernel(const int* __restrict__ dst, int* __restrict__ deg,
                            int* __restrict__ eidx, int E) {
  int e = blockIdx.x * blockDim.x + threadIdx.x;
  if (e < E) eidx[e] = atomicAdd(&deg[dst[e]], 1);
}

__global__ void dinv_kernel(const int* __restrict__ deg, float* __restrict__ dinv, int n) {
  int i = blockIdx.x * blockDim.x + threadIdx.x;
  if (i < n) dinv[i] = rsqrtf((float)(deg[i] + 1));  // +1 self loop
}

__global__ void partial_sum_kernel(const int* __restrict__ cnt, int* __restrict__ bsum, int n) {
  __shared__ int s[256];
  int i = blockIdx.x * 256 + threadIdx.x;
  s[threadIdx.x] = (i < n) ? cnt[i] : 0;
  __syncthreads();
  for (int off = 128; off > 0; off >>= 1) {
    if (threadIdx.x < off) s[threadIdx.x] += s[threadIdx.x + off];
    __syncthreads();
  }
  if (threadIdx.x == 0) bsum[blockIdx.x] = s[0];
}

__global__ void scan_bsum_kernel(const int* __restrict__ bsum, int* __restrict__ bexcl,
                                 int nb, int* __restrict__ rowptr_last) {
  __shared__ int s[256];
  int t = threadIdx.x;
  int v = (t < nb) ? bsum[t] : 0;
  s[t] = v;
  __syncthreads();
  for (int off = 1; off < 256; off <<= 1) {
    int add = (t >= off) ? s[t - off] : 0;
    __syncthreads();
    s[t] += add;
    __syncthreads();
  }
  if (t < nb) bexcl[t] = s[t] - v;
  if (t == 255) *rowptr_last = s[255];
}

__global__ void rowptr_kernel(const int* __restrict__ cnt, const int* __restrict__ bexcl,
                              int* __restrict__ rowptr, int n) {
  __shared__ int s[256];
  int i = blockIdx.x * 256 + threadIdx.x;
  int t = threadIdx.x;
  int v = (i < n) ? cnt[i] : 0;
  s[t] = v;
  __syncthreads();
  for (int off = 1; off < 256; off <<= 1) {
    int add = (t >= off) ? s[t - off] : 0;
    __syncthreads();
    s[t] += add;
    __syncthreads();
  }
  if (i < n) rowptr[i] = bexcl[blockIdx.x] + s[t] - v;
}

// no atomic: slot comes from hist's recorded arrival order. Pure independent 8B stores.
__global__ void fill_kernel(const int* __restrict__ src, const int* __restrict__ dst,
                            const float* __restrict__ dinv, const int* __restrict__ rowptr,
                            const int* __restrict__ eidx, int2* __restrict__ colwv, int E) {
  int e = blockIdx.x * blockDim.x + threadIdx.x;
  if (e >= E) return;
  int s = src[e], d = dst[e];
  int slot = rowptr[d] + eidx[e];
  int2 packed;
  packed.x = s;
  packed.y = __float_as_int(dinv[s] * dinv[d]);
  colwv[slot] = packed;
}

// ---------------- fp32 -> fp16 conversion (x, once) ----------------
__global__ void f32_to_f16_kernel(const float* __restrict__ in, __half* __restrict__ out,
                                  int total4) {  // total4 = elements/4
  int i = blockIdx.x * blockDim.x + threadIdx.x;
  if (i >= total4) return;
  float4 v = ((const float4*)in)[i];
  half4v o;
  o.a = __floats2half2_rn(v.x, v.y);
  o.b = __floats2half2_rn(v.z, v.w);
  ((half4v*)out)[i] = o;
}

// ---------------- aggregation (fp16 features): agg[i] = dinv^2*h[i] + sum wv*h[col] ----------
// One wave per node, half4v (8B) gathers. D=128: 32 lanes/edge, 2 edges/group.
// D=64: 16 lanes/edge, 4 edges/group. 8 gathers in flight.
template <int D>
__global__ __launch_bounds__(256) void aggregate_h_kernel(
    const __half* __restrict__ h, const int* __restrict__ rowptr,
    const int2* __restrict__ colwv, const float* __restrict__ dinv,
    float* __restrict__ out, int n) {
  int wid = (blockIdx.x * 256 + threadIdx.x) >> 6;
  int lane = threadIdx.x & 63;
  if (wid >= n) return;
  float di = dinv[wid];
  float sl = di * di;
  int beg = rowptr[wid], end = rowptr[wid + 1];
  const half4v* h4 = (const half4v*)h;  // D/4 half4v per row
  constexpr int RQ = D / 4;             // half4v per row (32 or 16)
  float4 acc = {0.f, 0.f, 0.f, 0.f};
  constexpr int EPG = (D == 128) ? 2 : 4;  // edges per instruction-group
  const int sub = (D == 128) ? (lane >> 5) : (lane >> 4);  // which edge in group
  const int lq = (D == 128) ? (lane & 31) : (lane & 15);   // feature quad
  for (int base = beg; base < end; base += 64) {
    int kk = base + lane;
    int c = 0; float ww = 0.f;  // tail lanes: weight 0 -> row-0 load harmless
    if (kk < end) { int2 e = colwv[kk]; c = e.x; ww = __int_as_float(e.y); }
    int m = end - base; if (m > 64) m = 64;
    for (int t0 = 0; t0 < m; t0 += 8 * EPG) {
      half4v v[8]; float ws[8];
      #pragma unroll
      for (int u = 0; u < 8; ++u) {
        int t = t0 + EPG * u + sub;  // <= 63 always
        int cs = __shfl(c, t);
        ws[u] = __shfl(ww, t);
        v[u] = h4[(size_t)cs * RQ + lq];
      }
      #pragma unroll
      for (int u = 0; u < 8; ++u) {
        float2 fa = __half22float2(v[u].a);
        float2 fb = __half22float2(v[u].b);
        acc.x += ws[u] * fa.x; acc.y += ws[u] * fa.y;
        acc.z += ws[u] * fb.x; acc.w += ws[u] * fb.y;
      }
    }
  }
  if constexpr (D == 64) {
    acc.x += __shfl_xor(acc.x, 16); acc.y += __shfl_xor(acc.y, 16);
    acc.z += __shfl_xor(acc.z, 16); acc.w += __shfl_xor(acc.w, 16);
  }
  acc.x += __shfl_xor(acc.x, 32); acc.y += __shfl_xor(acc.y, 32);
  acc.z += __shfl_xor(acc.z, 32); acc.w += __shfl_xor(acc.w, 32);
  if (lane < RQ) {  // RQ lanes write the row (lq == lane there)
    half4v hv = h4[(size_t)wid * RQ + lane];
    float2 fa = __half22float2(hv.a);
    float2 fb = __half22float2(hv.b);
    acc.x += sl * fa.x; acc.y += sl * fa.y; acc.z += sl * fb.x; acc.w += sl * fb.y;
    ((float4*)out)[(size_t)wid * RQ + lane] = acc;
  }
}

// ---------------- C = relu(A @ W + b) -> fp16, A[n,K] fp32, W[K,128] ----------------
template <int K>
__global__ __launch_bounds__(256) void gemm_bias_relu_kernel(
    const float* __restrict__ A, const float* __restrict__ W, const float* __restrict__ bias,
    __half* __restrict__ C, int n) {
  constexpr int BM = 64, BN = 128, BK = 32;
  __shared__ float At[BK][BM + 4];  // transposed A tile
  __shared__ float Ws[BK][BN];
  const int tid = threadIdx.x;
  const int block_row = blockIdx.x * BM;
  const int tr = tid >> 4, tc = tid & 15;
  const int row0 = tr * 4, col0 = tc * 8;
  float acc[4][8] = {};
  for (int kb = 0; kb < K; kb += BK) {
    {  // A tile: 64x32, 8 floats/thread
      int r = tid >> 2;
      int k = (tid & 3) * 8;
      int grow = block_row + r;
      float4 v0 = {0, 0, 0, 0}, v1 = {0, 0, 0, 0};
      if (grow < n) {
        v0 = *(const float4*)&A[(size_t)grow * K + kb + k];
        v1 = *(const float4*)&A[(size_t)grow * K + kb + k + 4];
      }
      At[k + 0][r] = v0.x; At[k + 1][r] = v0.y; At[k + 2][r] = v0.z; At[k + 3][r] = v0.w;
      At[k + 4][r] = v1.x; At[k + 5][r] = v1.y; At[k + 6][r] = v1.z; At[k + 7][r] = v1.w;
    }
    #pragma unroll
    for (int t = 0; t < 4; ++t) {  // W tile: 32x128 = 1024 float4, 4/thread
      int idx4 = tid + t * 256;
      int k = idx4 >> 5;
      int c4 = idx4 & 31;
      *(float4*)&Ws[k][c4 * 4] = *(const float4*)&W[(size_t)(kb + k) * BN + c4 * 4];
    }
    __syncthreads();
    #pragma unroll
    for (int k = 0; k < BK; ++k) {
      float a[4], w[8];
      *(float4*)&a[0] = *(const float4*)&At[k][row0];
      *(float4*)&w[0] = *(const float4*)&Ws[k][col0];
      *(float4*)&w[4] = *(const float4*)&Ws[k][col0 + 4];
      #pragma unroll
      for (int i = 0; i < 4; ++i)
        #pragma unroll
        for (int j = 0; j < 8; ++j)
          acc[i][j] += a[i] * w[j];
    }
    __syncthreads();
  }
  #pragma unroll
  for (int i = 0; i < 4; ++i) {
    int grow = block_row + row0 + i;
    if (grow >= n) continue;
    alignas(16) __half o[8];
    #pragma unroll
    for (int j = 0; j < 8; ++j) o[j] = __float2half(fmaxf(acc[i][j] + bias[col0 + j], 0.f));
    *(uint4*)&C[(size_t)grow * BN + col0] = *(uint4*)&o[0];  // 8 halves = 16B
  }
}

// ---------------- pooling: sorted batch_index => segmented mean over fp16 h ----------------
__global__ __launch_bounds__(128) void pool_mean_kernel(
    const __half* __restrict__ h, const int* __restrict__ batch,
    float* __restrict__ pooled, int n) {
  int b = blockIdx.x;
  int lo = 0, hi = n;
  while (lo < hi) { int mid = (lo + hi) >> 1; if (batch[mid] < b) lo = mid + 1; else hi = mid; }
  int s = lo;
  hi = n;
  while (lo < hi) { int mid = (lo + hi) >> 1; if (batch[mid] < b + 1) lo = mid + 1; else hi = mid; }
  int e = lo;
  int t = threadIdx.x;  // feature t of 128; 256B contiguous per node
  float acc = 0.f;
  for (int i = s; i < e; ++i) acc += __half2float(h[(size_t)i * 128 + t]);
  float c = fmaxf((float)(e - s), 1.0f);
  pooled[b * 128 + t] = acc / c;
}

// ---------------- per-graph MLP head ----------------
__global__ __launch_bounds__(128) void mlp_kernel(
    const float* __restrict__ pooled,
    const float* __restrict__ lW1, const float* __restrict__ lb1,
    const float* __restrict__ lW2, const float* __restrict__ lb2,
    const float* __restrict__ gamma, const float* __restrict__ beta,
    const float* __restrict__ rm, const float* __restrict__ rv,
    const float* __restrict__ oW, const float* __restrict__ ob,
    float* __restrict__ out, int B) {
  int b = blockIdx.x, t = threadIdx.x;
  __shared__ float p[128], h1[128];
  p[t] = pooled[b * 128 + t];
  __syncthreads();
  float a1 = lb1[t];
  for (int k = 0; k < 128; ++k) a1 += p[k] * lW1[k * 128 + t];
  h1[t] = a1;
  __syncthreads();
  if (t < 64) {
    float a2 = lb2[t];
    for (int k = 0; k < 128; ++k) a2 += h1[k] * lW2[k * 64 + t];
    a2 = (a2 - rm[t]) * gamma[t] * rsqrtf(rv[t] + 1e-5f) + beta[t];
    float hd = fmaxf(a2, 0.f);
    out[B + b * 64 + t] = hd;  // hidden, output 1
    float prod = hd * oW[t];
    #pragma unroll
    for (int off = 32; off > 0; off >>= 1) prod += __shfl_down(prod, off);
    if (t == 0) out[b] = prod + ob[0];  // out, output 0
  }
}

extern "C" void kernel_launch(void* const* d_in, const int* in_sizes, int n_in,
                              void* d_out, int out_size, void* d_ws, size_t ws_size,
                              hipStream_t stream) {
  const float* x = (const float*)d_in[0];
  const int* ei = (const int*)d_in[1];
  const int* batch = (const int*)d_in[2];
  const float* W1 = (const float*)d_in[3];  const float* b1 = (const float*)d_in[4];
  const float* W2 = (const float*)d_in[5];  const float* b2 = (const float*)d_in[6];
  const float* W3 = (const float*)d_in[7];  const float* b3 = (const float*)d_in[8];
  const float* W4 = (const float*)d_in[9];  const float* b4 = (const float*)d_in[10];
  const float* lW1 = (const float*)d_in[11]; const float* lb1 = (const float*)d_in[12];
  const float* lW2 = (const float*)d_in[13]; const float* lb2 = (const float*)d_in[14];
  const float* gamma = (const float*)d_in[15]; const float* beta = (const float*)d_in[16];
  const float* rm = (const float*)d_in[17]; const float* rv = (const float*)d_in[18];
  const float* oW = (const float*)d_in[19]; const float* ob = (const float*)d_in[20];

  const int n = in_sizes[2];
  const int E = in_sizes[1] / 2;
  const int B = out_size / 65;  // out_size = B + B*64
  const int* src = ei;
  const int* dst = ei + E;

  char* ws = (char*)d_ws;
  size_t off = 0;
  auto alloc = [&](size_t bytes) -> void* {
    void* p = ws + off;
    off += (bytes + 255) & ~(size_t)255;
    return p;
  };
  int* deg = (int*)alloc((size_t)n * 4);
  float* dinv = (float*)alloc((size_t)n * 4);
  int* rowptr = (int*)alloc((size_t)(n + 1) * 4);
  int* eidx = (int*)alloc((size_t)E * 4);
  int* bsum = (int*)alloc(256 * 4);
  int* bexcl = (int*)alloc(256 * 4);
  int2* colwv = (int2*)alloc((size_t)E * 8);
  float* agg = (float*)alloc((size_t)n * 128 * 4);
  __half* hbuf = (__half*)alloc((size_t)n * 128 * 2);
  __half* xh = (__half*)alloc((size_t)n * 64 * 2);
  float* pooled = (float*)alloc((size_t)B * 128 * 4);

  hipMemsetAsync(deg, 0, (size_t)n * 4, stream);

  const int nb = (n + 255) / 256;  // 196 blocks <= 256, fits single-block scan
  hist_kernel<<<(E + 255) / 256, 256, 0, stream>>>(dst, deg, eidx, E);
  f32_to_f16_kernel<<<(n * 16 + 255) / 256, 256, 0, stream>>>(x, xh, n * 16);  // n*64/4
  dinv_kernel<<<nb, 256, 0, stream>>>(deg, dinv, n);
  partial_sum_kernel<<<nb, 256, 0, stream>>>(deg, bsum, n);
  scan_bsum_kernel<<<1, 256, 0, stream>>>(bsum, bexcl, nb, rowptr + n);
  rowptr_kernel<<<nb, 256, 0, stream>>>(deg, bexcl, rowptr, n);
  fill_kernel<<<(E + 255) / 256, 256, 0, stream>>>(src, dst, dinv, rowptr, eidx, colwv, E);

  const int aggblocks = (n + 3) / 4;     // 4 waves (nodes) per block
  const int gemmblocks = (n + 63) / 64;  // 64 rows per block

  aggregate_h_kernel<64><<<aggblocks, 256, 0, stream>>>(xh, rowptr, colwv, dinv, agg, n);
  gemm_bias_relu_kernel<64><<<gemmblocks, 256, 0, stream>>>(agg, W1, b1, hbuf, n);
  aggregate_h_kernel<128><<<aggblocks, 256, 0, stream>>>(hbuf, rowptr, colwv, dinv, agg, n);
  gemm_bias_relu_kernel<128><<<gemmblocks, 256, 0, stream>>>(agg, W2, b2, hbuf, n);
  aggregate_h_kernel<128><<<aggblocks, 256, 0, stream>>>(hbuf, rowptr, colwv, dinv, agg, n);
  gemm_bias_relu_kernel<128><<<gemmblocks, 256, 0, stream>>>(agg, W3, b3, hbuf, n);
  aggregate_h_kernel<128><<<aggblocks, 256, 0, stream>>>(hbuf, rowptr, colwv, dinv, agg, n);
  gemm_bias_relu_kernel<128><<<gemmblocks, 256, 0, stream>>>(agg, W4, b4, hbuf, n);

  pool_mean_kernel<<<B, 128, 0, stream>>>(hbuf, batch, pooled, n);
  mlp_kernel<<<B, 128, 0, stream>>>(pooled, lW1, lb1, lW2, lb2, gamma, beta, rm, rv, oW, ob,
                                    (float*)d_out, B);
}

// Round 13
// 324.063 us; speedup vs baseline: 1.8737x; 1.0799x over previous
//
#include <hip/hip_runtime.h>
#include <hip/hip_fp16.h>

struct alignas(8) half4v { __half2 a, b; };  // 4 halves, 8B

__global__ void zero_kernel(int* __restrict__ p, int n) {
  int i = blockIdx.x * blockDim.x + threadIdx.x;
  if (i < n) p[i] = 0;
}

// ---------------- CSR build ----------------
// hist also records each edge's arrival order within its dst row -> fill needs no cursor atomic
__global__ void hist_kernel(const int* __restrict__ dst, int* __restrict__ deg,
                            int* __restrict__ eidx, int E) {
  int e = blockIdx.x * blockDim.x + threadIdx.x;
  if (e < E) eidx[e] = atomicAdd(&deg[dst[e]], 1);
}

__global__ void dinv_kernel(const int* __restrict__ deg, float* __restrict__ dinv, int n) {
  int i = blockIdx.x * blockDim.x + threadIdx.x;
  if (i < n) dinv[i] = rsqrtf((float)(deg[i] + 1));  // +1 self loop
}

__global__ void partial_sum_kernel(const int* __restrict__ cnt, int* __restrict__ bsum, int n) {
  __shared__ int s[256];
  int i = blockIdx.x * 256 + threadIdx.x;
  s[threadIdx.x] = (i < n) ? cnt[i] : 0;
  __syncthreads();
  for (int off = 128; off > 0; off >>= 1) {
    if (threadIdx.x < off) s[threadIdx.x] += s[threadIdx.x + off];
    __syncthreads();
  }
  if (threadIdx.x == 0) bsum[blockIdx.x] = s[0];
}

__global__ void scan_bsum_kernel(const int* __restrict__ bsum, int* __restrict__ bexcl,
                                 int nb, int* __restrict__ rowptr_last) {
  __shared__ int s[256];
  int t = threadIdx.x;
  int v = (t < nb) ? bsum[t] : 0;
  s[t] = v;
  __syncthreads();
  for (int off = 1; off < 256; off <<= 1) {
    int add = (t >= off) ? s[t - off] : 0;
    __syncthreads();
    s[t] += add;
    __syncthreads();
  }
  if (t < nb) bexcl[t] = s[t] - v;
  if (t == 255) *rowptr_last = s[255];
}

__global__ void rowptr_kernel(const int* __restrict__ cnt, const int* __restrict__ bexcl,
                              int* __restrict__ rowptr, int n) {
  __shared__ int s[256];
  int i = blockIdx.x * 256 + threadIdx.x;
  int t = threadIdx.x;
  int v = (i < n) ? cnt[i] : 0;
  s[t] = v;
  __syncthreads();
  for (int off = 1; off < 256; off <<= 1) {
    int add = (t >= off) ? s[t - off] : 0;
    __syncthreads();
    s[t] += add;
    __syncthreads();
  }
  if (i < n) rowptr[i] = bexcl[blockIdx.x] + s[t] - v;
}

// no atomic: slot comes from hist's recorded arrival order. Pure independent 8B stores.
__global__ void fill_kernel(const int* __restrict__ src, const int* __restrict__ dst,
                            const float* __restrict__ dinv, const int* __restrict__ rowptr,
                            const int* __restrict__ eidx, int2* __restrict__ colwv, int E) {
  int e = blockIdx.x * blockDim.x + threadIdx.x;
  if (e >= E) return;
  int s = src[e], d = dst[e];
  int slot = rowptr[d] + eidx[e];
  int2 packed;
  packed.x = s;
  packed.y = __float_as_int(dinv[s] * dinv[d]);
  colwv[slot] = packed;
}

// ---------------- fp32 -> fp16 conversion (x, once) ----------------
__global__ void f32_to_f16_kernel(const float* __restrict__ in, __half* __restrict__ out,
                                  int total4) {  // total4 = elements/4
  int i = blockIdx.x * blockDim.x + threadIdx.x;
  if (i >= total4) return;
  float4 v = ((const float4*)in)[i];
  half4v o;
  o.a = __floats2half2_rn(v.x, v.y);
  o.b = __floats2half2_rn(v.z, v.w);
  ((half4v*)out)[i] = o;
}

// ---------------- aggregation (fp16 features): agg[i] = dinv^2*h[i] + sum wv*h[col] ----------
// One wave per node, half4v (8B) gathers. D=128: 32 lanes/edge, 2 edges/group.
// D=64: 16 lanes/edge, 4 edges/group. 8 gathers in flight.
template <int D>
__global__ __launch_bounds__(256) void aggregate_h_kernel(
    const __half* __restrict__ h, const int* __restrict__ rowptr,
    const int2* __restrict__ colwv, const float* __restrict__ dinv,
    float* __restrict__ out, int n) {
  int wid = (blockIdx.x * 256 + threadIdx.x) >> 6;
  int lane = threadIdx.x & 63;
  if (wid >= n) return;
  float di = dinv[wid];
  float sl = di * di;
  int beg = rowptr[wid], end = rowptr[wid + 1];
  const half4v* h4 = (const half4v*)h;  // D/4 half4v per row
  constexpr int RQ = D / 4;             // half4v per row (32 or 16)
  float4 acc = {0.f, 0.f, 0.f, 0.f};
  constexpr int EPG = (D == 128) ? 2 : 4;  // edges per instruction-group
  const int sub = (D == 128) ? (lane >> 5) : (lane >> 4);  // which edge in group
  const int lq = (D == 128) ? (lane & 31) : (lane & 15);   // feature quad
  for (int base = beg; base < end; base += 64) {
    int kk = base + lane;
    int c = 0; float ww = 0.f;  // tail lanes: weight 0 -> row-0 load harmless
    if (kk < end) { int2 e = colwv[kk]; c = e.x; ww = __int_as_float(e.y); }
    int m = end - base; if (m > 64) m = 64;
    for (int t0 = 0; t0 < m; t0 += 8 * EPG) {
      half4v v[8]; float ws[8];
      #pragma unroll
      for (int u = 0; u < 8; ++u) {
        int t = t0 + EPG * u + sub;  // <= 63 always
        int cs = __shfl(c, t);
        ws[u] = __shfl(ww, t);
        v[u] = h4[(size_t)cs * RQ + lq];
      }
      #pragma unroll
      for (int u = 0; u < 8; ++u) {
        float2 fa = __half22float2(v[u].a);
        float2 fb = __half22float2(v[u].b);
        acc.x += ws[u] * fa.x; acc.y += ws[u] * fa.y;
        acc.z += ws[u] * fb.x; acc.w += ws[u] * fb.y;
      }
    }
  }
  if constexpr (D == 64) {
    acc.x += __shfl_xor(acc.x, 16); acc.y += __shfl_xor(acc.y, 16);
    acc.z += __shfl_xor(acc.z, 16); acc.w += __shfl_xor(acc.w, 16);
  }
  acc.x += __shfl_xor(acc.x, 32); acc.y += __shfl_xor(acc.y, 32);
  acc.z += __shfl_xor(acc.z, 32); acc.w += __shfl_xor(acc.w, 32);
  if (lane < RQ) {  // RQ lanes write the row (lq == lane there)
    half4v hv = h4[(size_t)wid * RQ + lane];
    float2 fa = __half22float2(hv.a);
    float2 fb = __half22float2(hv.b);
    acc.x += sl * fa.x; acc.y += sl * fa.y; acc.z += sl * fb.x; acc.w += sl * fb.y;
    ((float4*)out)[(size_t)wid * RQ + lane] = acc;
  }
}

// ---------------- C = relu(A @ W + b) -> fp16, A[n,K] fp32, W[K,128] ----------------
template <int K>
__global__ __launch_bounds__(256) void gemm_bias_relu_kernel(
    const float* __restrict__ A, const float* __restrict__ W, const float* __restrict__ bias,
    __half* __restrict__ C, int n) {
  constexpr int BM = 64, BN = 128, BK = 32;
  __shared__ float At[BK][BM + 4];  // transposed A tile
  __shared__ float Ws[BK][BN];
  const int tid = threadIdx.x;
  const int block_row = blockIdx.x * BM;
  const int tr = tid >> 4, tc = tid & 15;
  const int row0 = tr * 4, col0 = tc * 8;
  float acc[4][8] = {};
  for (int kb = 0; kb < K; kb += BK) {
    {  // A tile: 64x32, 8 floats/thread
      int r = tid >> 2;
      int k = (tid & 3) * 8;
      int grow = block_row + r;
      float4 v0 = {0, 0, 0, 0}, v1 = {0, 0, 0, 0};
      if (grow < n) {
        v0 = *(const float4*)&A[(size_t)grow * K + kb + k];
        v1 = *(const float4*)&A[(size_t)grow * K + kb + k + 4];
      }
      At[k + 0][r] = v0.x; At[k + 1][r] = v0.y; At[k + 2][r] = v0.z; At[k + 3][r] = v0.w;
      At[k + 4][r] = v1.x; At[k + 5][r] = v1.y; At[k + 6][r] = v1.z; At[k + 7][r] = v1.w;
    }
    #pragma unroll
    for (int t = 0; t < 4; ++t) {  // W tile: 32x128 = 1024 float4, 4/thread
      int idx4 = tid + t * 256;
      int k = idx4 >> 5;
      int c4 = idx4 & 31;
      *(float4*)&Ws[k][c4 * 4] = *(const float4*)&W[(size_t)(kb + k) * BN + c4 * 4];
    }
    __syncthreads();
    #pragma unroll
    for (int k = 0; k < BK; ++k) {
      float a[4], w[8];
      *(float4*)&a[0] = *(const float4*)&At[k][row0];
      *(float4*)&w[0] = *(const float4*)&Ws[k][col0];
      *(float4*)&w[4] = *(const float4*)&Ws[k][col0 + 4];
      #pragma unroll
      for (int i = 0; i < 4; ++i)
        #pragma unroll
        for (int j = 0; j < 8; ++j)
          acc[i][j] += a[i] * w[j];
    }
    __syncthreads();
  }
  #pragma unroll
  for (int i = 0; i < 4; ++i) {
    int grow = block_row + row0 + i;
    if (grow >= n) continue;
    alignas(16) __half o[8];
    #pragma unroll
    for (int j = 0; j < 8; ++j) o[j] = __float2half(fmaxf(acc[i][j] + bias[col0 + j], 0.f));
    *(uint4*)&C[(size_t)grow * BN + col0] = *(uint4*)&o[0];  // 8 halves = 16B
  }
}

// ---------------- pooling: segmented mean, 8-way node-parallel + half4v loads ----------------
__global__ __launch_bounds__(256) void pool_mean_kernel(
    const __half* __restrict__ h, const int* __restrict__ batch,
    float* __restrict__ pooled, int n) {
  int b = blockIdx.x;
  int lo = 0, hi = n;
  while (lo < hi) { int mid = (lo + hi) >> 1; if (batch[mid] < b) lo = mid + 1; else hi = mid; }
  int s = lo;
  hi = n;
  while (lo < hi) { int mid = (lo + hi) >> 1; if (batch[mid] < b + 1) lo = mid + 1; else hi = mid; }
  int e = lo;
  const half4v* h4 = (const half4v*)h;  // 32 quads per 128-feature row
  int q = threadIdx.x & 31;   // feature quad
  int r = threadIdx.x >> 5;   // node-parallel slot 0..7
  float4 acc = {0.f, 0.f, 0.f, 0.f};
  for (int i = s + r; i < e; i += 8) {   // coalesced: 32 consecutive 8B per row-slot
    half4v v = h4[(size_t)i * 32 + q];
    float2 fa = __half22float2(v.a), fb = __half22float2(v.b);
    acc.x += fa.x; acc.y += fa.y; acc.z += fb.x; acc.w += fb.y;
  }
  __shared__ float4 red[8][32];
  red[r][q] = acc;
  __syncthreads();
  for (int off = 4; off > 0; off >>= 1) {
    if (r < off) {
      float4 o = red[r + off][q];
      acc.x += o.x; acc.y += o.y; acc.z += o.z; acc.w += o.w;
      red[r][q] = acc;
    }
    __syncthreads();
  }
  if (r == 0) {
    float c = fmaxf((float)(e - s), 1.0f);
    float4 o;
    o.x = acc.x / c; o.y = acc.y / c; o.z = acc.z / c; o.w = acc.w / c;
    ((float4*)pooled)[b * 32 + q] = o;
  }
}

// ---------------- per-graph MLP head ----------------
__global__ __launch_bounds__(128) void mlp_kernel(
    const float* __restrict__ pooled,
    const float* __restrict__ lW1, const float* __restrict__ lb1,
    const float* __restrict__ lW2, const float* __restrict__ lb2,
    const float* __restrict__ gamma, const float* __restrict__ beta,
    const float* __restrict__ rm, const float* __restrict__ rv,
    const float* __restrict__ oW, const float* __restrict__ ob,
    float* __restrict__ out, int B) {
  int b = blockIdx.x, t = threadIdx.x;
  __shared__ float p[128], h1[128];
  p[t] = pooled[b * 128 + t];
  __syncthreads();
  float a1 = lb1[t];
  for (int k = 0; k < 128; ++k) a1 += p[k] * lW1[k * 128 + t];
  h1[t] = a1;
  __syncthreads();
  if (t < 64) {
    float a2 = lb2[t];
    for (int k = 0; k < 128; ++k) a2 += h1[k] * lW2[k * 64 + t];
    a2 = (a2 - rm[t]) * gamma[t] * rsqrtf(rv[t] + 1e-5f) + beta[t];
    float hd = fmaxf(a2, 0.f);
    out[B + b * 64 + t] = hd;  // hidden, output 1
    float prod = hd * oW[t];
    #pragma unroll
    for (int off = 32; off > 0; off >>= 1) prod += __shfl_down(prod, off);
    if (t == 0) out[b] = prod + ob[0];  // out, output 0
  }
}

extern "C" void kernel_launch(void* const* d_in, const int* in_sizes, int n_in,
                              void* d_out, int out_size, void* d_ws, size_t ws_size,
                              hipStream_t stream) {
  const float* x = (const float*)d_in[0];
  const int* ei = (const int*)d_in[1];
  const int* batch = (const int*)d_in[2];
  const float* W1 = (const float*)d_in[3];  const float* b1 = (const float*)d_in[4];
  const float* W2 = (const float*)d_in[5];  const float* b2 = (const float*)d_in[6];
  const float* W3 = (const float*)d_in[7];  const float* b3 = (const float*)d_in[8];
  const float* W4 = (const float*)d_in[9];  const float* b4 = (const float*)d_in[10];
  const float* lW1 = (const float*)d_in[11]; const float* lb1 = (const float*)d_in[12];
  const float* lW2 = (const float*)d_in[13]; const float* lb2 = (const float*)d_in[14];
  const float* gamma = (const float*)d_in[15]; const float* beta = (const float*)d_in[16];
  const float* rm = (const float*)d_in[17]; const float* rv = (const float*)d_in[18];
  const float* oW = (const float*)d_in[19]; const float* ob = (const float*)d_in[20];

  const int n = in_sizes[2];
  const int E = in_sizes[1] / 2;
  const int B = out_size / 65;  // out_size = B + B*64
  const int* src = ei;
  const int* dst = ei + E;

  char* ws = (char*)d_ws;
  size_t off = 0;
  auto alloc = [&](size_t bytes) -> void* {
    void* p = ws + off;
    off += (bytes + 255) & ~(size_t)255;
    return p;
  };
  int* deg = (int*)alloc((size_t)n * 4);
  float* dinv = (float*)alloc((size_t)n * 4);
  int* rowptr = (int*)alloc((size_t)(n + 1) * 4);
  int* eidx = (int*)alloc((size_t)E * 4);
  int* bsum = (int*)alloc(256 * 4);
  int* bexcl = (int*)alloc(256 * 4);
  int2* colwv = (int2*)alloc((size_t)E * 8);
  float* agg = (float*)alloc((size_t)n * 128 * 4);
  __half* hbuf = (__half*)alloc((size_t)n * 128 * 2);
  __half* xh = (__half*)alloc((size_t)n * 64 * 2);
  float* pooled = (float*)alloc((size_t)B * 128 * 4);

  const int nb = (n + 255) / 256;  // 196 blocks <= 256, fits single-block scan
  zero_kernel<<<nb, 256, 0, stream>>>(deg, n);
  hist_kernel<<<(E + 255) / 256, 256, 0, stream>>>(dst, deg, eidx, E);
  f32_to_f16_kernel<<<(n * 16 + 255) / 256, 256, 0, stream>>>(x, xh, n * 16);  // n*64/4
  dinv_kernel<<<nb, 256, 0, stream>>>(deg, dinv, n);
  partial_sum_kernel<<<nb, 256, 0, stream>>>(deg, bsum, n);
  scan_bsum_kernel<<<1, 256, 0, stream>>>(bsum, bexcl, nb, rowptr + n);
  rowptr_kernel<<<nb, 256, 0, stream>>>(deg, bexcl, rowptr, n);
  fill_kernel<<<(E + 255) / 256, 256, 0, stream>>>(src, dst, dinv, rowptr, eidx, colwv, E);

  const int aggblocks = (n + 3) / 4;     // 4 waves (nodes) per block
  const int gemmblocks = (n + 63) / 64;  // 64 rows per block

  aggregate_h_kernel<64><<<aggblocks, 256, 0, stream>>>(xh, rowptr, colwv, dinv, agg, n);
  gemm_bias_relu_kernel<64><<<gemmblocks, 256, 0, stream>>>(agg, W1, b1, hbuf, n);
  aggregate_h_kernel<128><<<aggblocks, 256, 0, stream>>>(hbuf, rowptr, colwv, dinv, agg, n);
  gemm_bias_relu_kernel<128><<<gemmblocks, 256, 0, stream>>>(agg, W2, b2, hbuf, n);
  aggregate_h_kernel<128><<<aggblocks, 256, 0, stream>>>(hbuf, rowptr, colwv, dinv, agg, n);
  gemm_bias_relu_kernel<128><<<gemmblocks, 256, 0, stream>>>(agg, W3, b3, hbuf, n);
  aggregate_h_kernel<128><<<aggblocks, 256, 0, stream>>>(hbuf, rowptr, colwv, dinv, agg, n);
  gemm_bias_relu_kernel<128><<<gemmblocks, 256, 0, stream>>>(agg, W4, b4, hbuf, n);

  pool_mean_kernel<<<B, 256, 0, stream>>>(hbuf, batch, pooled, n);
  mlp_kernel<<<B, 128, 0, stream>>>(pooled, lW1, lb1, lW2, lb2, gamma, beta, rm, rv, oW, ob,
                                    (float*)d_out, B);
}

// Round 15
// 278.570 us; speedup vs baseline: 2.1797x; 1.1633x over previous
//
#include <hip/hip_runtime.h>
#include <hip/hip_fp16.h>

struct alignas(8) half4v { __half2 a, b; };  // 4 halves, 8B
using f16x8 = __attribute__((ext_vector_type(8))) _Float16;  // 4 VGPRs
using f32x4 = __attribute__((ext_vector_type(4))) float;

__global__ void zero_kernel(int* __restrict__ p, int n) {
  int i = blockIdx.x * blockDim.x + threadIdx.x;
  if (i < n) p[i] = 0;
}

// ---------------- CSR build ----------------
__global__ void hist_kernel(const int* __restrict__ dst, int* __restrict__ deg,
                            int* __restrict__ eidx, int E) {
  int e = blockIdx.x * blockDim.x + threadIdx.x;
  if (e < E) eidx[e] = atomicAdd(&deg[dst[e]], 1);
}

__global__ void dinv_kernel(const int* __restrict__ deg, float* __restrict__ dinv, int n) {
  int i = blockIdx.x * blockDim.x + threadIdx.x;
  if (i < n) dinv[i] = rsqrtf((float)(deg[i] + 1));  // +1 self loop
}

__global__ void partial_sum_kernel(const int* __restrict__ cnt, int* __restrict__ bsum, int n) {
  __shared__ int s[256];
  int i = blockIdx.x * 256 + threadIdx.x;
  s[threadIdx.x] = (i < n) ? cnt[i] : 0;
  __syncthreads();
  for (int off = 128; off > 0; off >>= 1) {
    if (threadIdx.x < off) s[threadIdx.x] += s[threadIdx.x + off];
    __syncthreads();
  }
  if (threadIdx.x == 0) bsum[blockIdx.x] = s[0];
}

__global__ void scan_bsum_kernel(const int* __restrict__ bsum, int* __restrict__ bexcl,
                                 int nb, int* __restrict__ rowptr_last) {
  __shared__ int s[256];
  int t = threadIdx.x;
  int v = (t < nb) ? bsum[t] : 0;
  s[t] = v;
  __syncthreads();
  for (int off = 1; off < 256; off <<= 1) {
    int add = (t >= off) ? s[t - off] : 0;
    __syncthreads();
    s[t] += add;
    __syncthreads();
  }
  if (t < nb) bexcl[t] = s[t] - v;
  if (t == 255) *rowptr_last = s[255];
}

__global__ void rowptr_kernel(const int* __restrict__ cnt, const int* __restrict__ bexcl,
                              int* __restrict__ rowptr, int n) {
  __shared__ int s[256];
  int i = blockIdx.x * 256 + threadIdx.x;
  int t = threadIdx.x;
  int v = (i < n) ? cnt[i] : 0;
  s[t] = v;
  __syncthreads();
  for (int off = 1; off < 256; off <<= 1) {
    int add = (t >= off) ? s[t - off] : 0;
    __syncthreads();
    s[t] += add;
    __syncthreads();
  }
  if (i < n) rowptr[i] = bexcl[blockIdx.x] + s[t] - v;
}

__global__ void fill_kernel(const int* __restrict__ src, const int* __restrict__ dst,
                            const float* __restrict__ dinv, const int* __restrict__ rowptr,
                            const int* __restrict__ eidx, int2* __restrict__ colwv, int E) {
  int e = blockIdx.x * blockDim.x + threadIdx.x;
  if (e >= E) return;
  int s = src[e], d = dst[e];
  int slot = rowptr[d] + eidx[e];
  int2 packed;
  packed.x = s;
  packed.y = __float_as_int(dinv[s] * dinv[d]);
  colwv[slot] = packed;
}

// ---------------- fp32 -> fp16 conversion (x, once) ----------------
__global__ void f32_to_f16_kernel(const float* __restrict__ in, __half* __restrict__ out,
                                  int total4) {
  int i = blockIdx.x * blockDim.x + threadIdx.x;
  if (i >= total4) return;
  float4 v = ((const float4*)in)[i];
  half4v o;
  o.a = __floats2half2_rn(v.x, v.y);
  o.b = __floats2half2_rn(v.z, v.w);
  ((half4v*)out)[i] = o;
}

// ---------------- pack W [K,128] fp32 -> MFMA B-fragment order fp16 ----------------
// Wp element ((ks*8 + c)*64 + lane)*8 + j  =  W[k][col],
//   k = ks*32 + (lane>>4)*8 + j, col = c*16 + (lane&15)   (16x16x32_f16 B layout)
template <int K>
__global__ void pack_w_kernel(const float* __restrict__ W, __half* __restrict__ Wp) {
  int idx = blockIdx.x * 256 + threadIdx.x;
  if (idx >= K * 128) return;
  int j = idx & 7;
  int lane = (idx >> 3) & 63;
  int c = (idx >> 9) & 7;
  int ks = idx >> 12;
  int k = ks * 32 + ((lane >> 4) << 3) + j;
  int col = c * 16 + (lane & 15);
  Wp[idx] = __float2half(W[k * 128 + col]);
}

// ---------------- aggregation (fp16 in/out): agg[i] = dinv^2*h[i] + sum wv*h[col] ----------
template <int D>
__global__ __launch_bounds__(256) void aggregate_h_kernel(
    const __half* __restrict__ h, const int* __restrict__ rowptr,
    const int2* __restrict__ colwv, const float* __restrict__ dinv,
    __half* __restrict__ out, int n) {
  int wid = (blockIdx.x * 256 + threadIdx.x) >> 6;
  int lane = threadIdx.x & 63;
  if (wid >= n) return;
  float di = dinv[wid];
  float sl = di * di;
  int beg = rowptr[wid], end = rowptr[wid + 1];
  const half4v* h4 = (const half4v*)h;
  constexpr int RQ = D / 4;  // half4v per row
  float4 acc = {0.f, 0.f, 0.f, 0.f};
  constexpr int EPG = (D == 128) ? 2 : 4;
  const int sub = (D == 128) ? (lane >> 5) : (lane >> 4);
  const int lq = (D == 128) ? (lane & 31) : (lane & 15);
  for (int base = beg; base < end; base += 64) {
    int kk = base + lane;
    int c = 0; float ww = 0.f;
    if (kk < end) { int2 e = colwv[kk]; c = e.x; ww = __int_as_float(e.y); }
    int m = end - base; if (m > 64) m = 64;
    for (int t0 = 0; t0 < m; t0 += 8 * EPG) {
      half4v v[8]; float ws[8];
      #pragma unroll
      for (int u = 0; u < 8; ++u) {
        int t = t0 + EPG * u + sub;
        int cs = __shfl(c, t);
        ws[u] = __shfl(ww, t);
        v[u] = h4[(size_t)cs * RQ + lq];
      }
      #pragma unroll
      for (int u = 0; u < 8; ++u) {
        float2 fa = __half22float2(v[u].a);
        float2 fb = __half22float2(v[u].b);
        acc.x += ws[u] * fa.x; acc.y += ws[u] * fa.y;
        acc.z += ws[u] * fb.x; acc.w += ws[u] * fb.y;
      }
    }
  }
  if constexpr (D == 64) {
    acc.x += __shfl_xor(acc.x, 16); acc.y += __shfl_xor(acc.y, 16);
    acc.z += __shfl_xor(acc.z, 16); acc.w += __shfl_xor(acc.w, 16);
  }
  acc.x += __shfl_xor(acc.x, 32); acc.y += __shfl_xor(acc.y, 32);
  acc.z += __shfl_xor(acc.z, 32); acc.w += __shfl_xor(acc.w, 32);
  if (lane < RQ) {
    half4v hv = h4[(size_t)wid * RQ + lane];
    float2 fa = __half22float2(hv.a);
    float2 fb = __half22float2(hv.b);
    acc.x += sl * fa.x; acc.y += sl * fa.y; acc.z += sl * fb.x; acc.w += sl * fb.y;
    half4v o;
    o.a = __floats2half2_rn(acc.x, acc.y);
    o.b = __floats2half2_rn(acc.z, acc.w);
    ((half4v*)out)[(size_t)wid * RQ + lane] = o;
  }
}

// ---------------- MFMA GEMM: C[n,128] = relu(A[n,K] @ W + bias), fp16 in/out, f32 acc -----
// 4 waves/block, wave handles 16 rows x 128 cols (8 col-tiles of 16x16, mfma_f32_16x16x32_f16).
// A frag: lane reads A[r0+(lane&15)][ks*32+(lane>>4)*8 .. +7] -- one 16B load.
// B frag: pre-packed Wp (L2-resident). C/D: col=lane&15, row=(lane>>4)*4+reg  [m89 verified].
template <int K>
__global__ __launch_bounds__(256) void gemm_mfma_kernel(
    const __half* __restrict__ A, const __half* __restrict__ Wp,
    const float* __restrict__ bias, __half* __restrict__ C, int n) {
  const int wave = threadIdx.x >> 6;
  const int lane = threadIdx.x & 63;
  const int r0 = blockIdx.x * 64 + wave * 16;
  const int arow = r0 + (lane & 15);
  const int kgrp = lane >> 4;
  f32x4 acc[8] = {};
  const f16x8* Wp8 = (const f16x8*)Wp;
  #pragma unroll
  for (int ks = 0; ks < K / 32; ++ks) {
    f16x8 afrag = {};
    if (arow < n) afrag = *(const f16x8*)&A[(size_t)arow * K + ks * 32 + kgrp * 8];
    #pragma unroll
    for (int c = 0; c < 8; ++c) {
      f16x8 bfrag = Wp8[(ks * 8 + c) * 64 + lane];
      acc[c] = __builtin_amdgcn_mfma_f32_16x16x32_f16(afrag, bfrag, acc[c], 0, 0, 0);
    }
  }
  const int colbase = lane & 15;
  #pragma unroll
  for (int c = 0; c < 8; ++c) {
    int col = c * 16 + colbase;
    float bv = bias[col];
    #pragma unroll
    for (int j = 0; j < 4; ++j) {
      int row = r0 + kgrp * 4 + j;
      if (row < n) C[(size_t)row * 128 + col] = __float2half(fmaxf(acc[c][j] + bv, 0.f));
    }
  }
}

// ---------------- pooling: segmented mean, 8-way node-parallel + half4v loads ----------------
__global__ __launch_bounds__(256) void pool_mean_kernel(
    const __half* __restrict__ h, const int* __restrict__ batch,
    float* __restrict__ pooled, int n) {
  int b = blockIdx.x;
  int lo = 0, hi = n;
  while (lo < hi) { int mid = (lo + hi) >> 1; if (batch[mid] < b) lo = mid + 1; else hi = mid; }
  int s = lo;
  hi = n;
  while (lo < hi) { int mid = (lo + hi) >> 1; if (batch[mid] < b + 1) lo = mid + 1; else hi = mid; }
  int e = lo;
  const half4v* h4 = (const half4v*)h;
  int q = threadIdx.x & 31;
  int r = threadIdx.x >> 5;
  float4 acc = {0.f, 0.f, 0.f, 0.f};
  for (int i = s + r; i < e; i += 8) {
    half4v v = h4[(size_t)i * 32 + q];
    float2 fa = __half22float2(v.a), fb = __half22float2(v.b);
    acc.x += fa.x; acc.y += fa.y; acc.z += fb.x; acc.w += fb.y;
  }
  __shared__ float4 red[8][32];
  red[r][q] = acc;
  __syncthreads();
  for (int off = 4; off > 0; off >>= 1) {
    if (r < off) {
      float4 o = red[r + off][q];
      acc.x += o.x; acc.y += o.y; acc.z += o.z; acc.w += o.w;
      red[r][q] = acc;
    }
    __syncthreads();
  }
  if (r == 0) {
    float c = fmaxf((float)(e - s), 1.0f);
    float4 o;
    o.x = acc.x / c; o.y = acc.y / c; o.z = acc.z / c; o.w = acc.w / c;
    ((float4*)pooled)[b * 32 + q] = o;
  }
}

// ---------------- per-graph MLP head ----------------
__global__ __launch_bounds__(128) void mlp_kernel(
    const float* __restrict__ pooled,
    const float* __restrict__ lW1, const float* __restrict__ lb1,
    const float* __restrict__ lW2, const float* __restrict__ lb2,
    const float* __restrict__ gamma, const float* __restrict__ beta,
    const float* __restrict__ rm, const float* __restrict__ rv,
    const float* __restrict__ oW, const float* __restrict__ ob,
    float* __restrict__ out, int B) {
  int b = blockIdx.x, t = threadIdx.x;
  __shared__ float p[128], h1[128];
  p[t] = pooled[b * 128 + t];
  __syncthreads();
  float a1 = lb1[t];
  for (int k = 0; k < 128; ++k) a1 += p[k] * lW1[k * 128 + t];
  h1[t] = a1;
  __syncthreads();
  if (t < 64) {
    float a2 = lb2[t];
    for (int k = 0; k < 128; ++k) a2 += h1[k] * lW2[k * 64 + t];
    a2 = (a2 - rm[t]) * gamma[t] * rsqrtf(rv[t] + 1e-5f) + beta[t];
    float hd = fmaxf(a2, 0.f);
    out[B + b * 64 + t] = hd;  // hidden, output 1
    float prod = hd * oW[t];
    #pragma unroll
    for (int off = 32; off > 0; off >>= 1) prod += __shfl_down(prod, off);
    if (t == 0) out[b] = prod + ob[0];  // out, output 0
  }
}

extern "C" void kernel_launch(void* const* d_in, const int* in_sizes, int n_in,
                              void* d_out, int out_size, void* d_ws, size_t ws_size,
                              hipStream_t stream) {
  const float* x = (const float*)d_in[0];
  const int* ei = (const int*)d_in[1];
  const int* batch = (const int*)d_in[2];
  const float* W1 = (const float*)d_in[3];  const float* b1 = (const float*)d_in[4];
  const float* W2 = (const float*)d_in[5];  const float* b2 = (const float*)d_in[6];
  const float* W3 = (const float*)d_in[7];  const float* b3 = (const float*)d_in[8];
  const float* W4 = (const float*)d_in[9];  const float* b4 = (const float*)d_in[10];
  const float* lW1 = (const float*)d_in[11]; const float* lb1 = (const float*)d_in[12];
  const float* lW2 = (const float*)d_in[13]; const float* lb2 = (const float*)d_in[14];
  const float* gamma = (const float*)d_in[15]; const float* beta = (const float*)d_in[16];
  const float* rm = (const float*)d_in[17]; const float* rv = (const float*)d_in[18];
  const float* oW = (const float*)d_in[19]; const float* ob = (const float*)d_in[20];

  const int n = in_sizes[2];
  const int E = in_sizes[1] / 2;
  const int B = out_size / 65;  // out_size = B + B*64
  const int* src = ei;
  const int* dst = ei + E;

  char* ws = (char*)d_ws;
  size_t off = 0;
  auto alloc = [&](size_t bytes) -> void* {
    void* p = ws + off;
    off += (bytes + 255) & ~(size_t)255;
    return p;
  };
  int* deg = (int*)alloc((size_t)n * 4);
  float* dinv = (float*)alloc((size_t)n * 4);
  int* rowptr = (int*)alloc((size_t)(n + 1) * 4);
  int* eidx = (int*)alloc((size_t)E * 4);
  int* bsum = (int*)alloc(256 * 4);
  int* bexcl = (int*)alloc(256 * 4);
  int2* colwv = (int2*)alloc((size_t)E * 8);
  __half* aggh = (__half*)alloc((size_t)n * 128 * 2);
  __half* hbuf = (__half*)alloc((size_t)n * 128 * 2);
  __half* xh = (__half*)alloc((size_t)n * 64 * 2);
  __half* Wp1 = (__half*)alloc(64 * 128 * 2);
  __half* Wp2 = (__half*)alloc(128 * 128 * 2);
  __half* Wp3 = (__half*)alloc(128 * 128 * 2);
  __half* Wp4 = (__half*)alloc(128 * 128 * 2);
  float* pooled = (float*)alloc((size_t)B * 128 * 4);

  const int nb = (n + 255) / 256;  // 196 blocks <= 256, fits single-block scan
  zero_kernel<<<nb, 256, 0, stream>>>(deg, n);
  hist_kernel<<<(E + 255) / 256, 256, 0, stream>>>(dst, deg, eidx, E);
  f32_to_f16_kernel<<<(n * 16 + 255) / 256, 256, 0, stream>>>(x, xh, n * 16);
  pack_w_kernel<64><<<32, 256, 0, stream>>>(W1, Wp1);
  pack_w_kernel<128><<<64, 256, 0, stream>>>(W2, Wp2);
  pack_w_kernel<128><<<64, 256, 0, stream>>>(W3, Wp3);
  pack_w_kernel<128><<<64, 256, 0, stream>>>(W4, Wp4);
  dinv_kernel<<<nb, 256, 0, stream>>>(deg, dinv, n);
  partial_sum_kernel<<<nb, 256, 0, stream>>>(deg, bsum, n);
  scan_bsum_kernel<<<1, 256, 0, stream>>>(bsum, bexcl, nb, rowptr + n);
  rowptr_kernel<<<nb, 256, 0, stream>>>(deg, bexcl, rowptr, n);
  fill_kernel<<<(E + 255) / 256, 256, 0, stream>>>(src, dst, dinv, rowptr, eidx, colwv, E);

  const int aggblocks = (n + 3) / 4;      // 4 waves (nodes) per block
  const int gemmblocks = (n + 63) / 64;   // 64 rows per block

  aggregate_h_kernel<64><<<aggblocks, 256, 0, stream>>>(xh, rowptr, colwv, dinv, aggh, n);
  gemm_mfma_kernel<64><<<gemmblocks, 256, 0, stream>>>(aggh, Wp1, b1, hbuf, n);
  aggregate_h_kernel<128><<<aggblocks, 256, 0, stream>>>(hbuf, rowptr, colwv, dinv, aggh, n);
  gemm_mfma_kernel<128><<<gemmblocks, 256, 0, stream>>>(aggh, Wp2, b2, hbuf, n);
  aggregate_h_kernel<128><<<aggblocks, 256, 0, stream>>>(hbuf, rowptr, colwv, dinv, aggh, n);
  gemm_mfma_kernel<128><<<gemmblocks, 256, 0, stream>>>(aggh, Wp3, b3, hbuf, n);
  aggregate_h_kernel<128><<<aggblocks, 256, 0, stream>>>(hbuf, rowptr, colwv, dinv, aggh, n);
  gemm_mfma_kernel<128><<<gemmblocks, 256, 0, stream>>>(aggh, Wp4, b4, hbuf, n);

  pool_mean_kernel<<<B, 256, 0, stream>>>(hbuf, batch, pooled, n);
  mlp_kernel<<<B, 128, 0, stream>>>(pooled, lW1, lb1, lW2, lb2, gamma, beta, rm, rv, oW, ob,
                                    (float*)d_out, B);
}

// Round 16
// 272.701 us; speedup vs baseline: 2.2266x; 1.0215x over previous
//
#include <hip/hip_runtime.h>
#include <hip/hip_fp16.h>

struct alignas(8) half4v { __half2 a, b; };  // 4 halves, 8B
using f16x8 = __attribute__((ext_vector_type(8))) _Float16;  // 4 VGPRs
using f32x4 = __attribute__((ext_vector_type(4))) float;

__global__ void zero_kernel(int* __restrict__ p, int n) {
  int i = blockIdx.x * blockDim.x + threadIdx.x;
  if (i < n) p[i] = 0;
}

// ---------------- CSR build ----------------
// 4 edges/thread: 4 independent atomic round-trips in flight (was 1 -> latency-chained)
__global__ void hist_kernel(const int* __restrict__ dst, int* __restrict__ deg,
                            int* __restrict__ eidx, int E) {
  int e0 = (blockIdx.x * blockDim.x + threadIdx.x) * 4;
  if (e0 + 3 < E) {
    int4 d4 = *(const int4*)&dst[e0];
    int r0 = atomicAdd(&deg[d4.x], 1);
    int r1 = atomicAdd(&deg[d4.y], 1);
    int r2 = atomicAdd(&deg[d4.z], 1);
    int r3 = atomicAdd(&deg[d4.w], 1);
    int4 o; o.x = r0; o.y = r1; o.z = r2; o.w = r3;
    *(int4*)&eidx[e0] = o;
  } else {
    for (int e = e0; e < E; ++e) eidx[e] = atomicAdd(&deg[dst[e]], 1);
  }
}

// fused: dinv + per-block deg sum (both read deg)
__global__ void dinv_bsum_kernel(const int* __restrict__ deg, float* __restrict__ dinv,
                                 int* __restrict__ bsum, int n) {
  __shared__ int s[256];
  int i = blockIdx.x * 256 + threadIdx.x;
  int d = (i < n) ? deg[i] : 0;
  if (i < n) dinv[i] = rsqrtf((float)(d + 1));  // +1 self loop
  s[threadIdx.x] = d;
  __syncthreads();
  for (int off = 128; off > 0; off >>= 1) {
    if (threadIdx.x < off) s[threadIdx.x] += s[threadIdx.x + off];
    __syncthreads();
  }
  if (threadIdx.x == 0) bsum[blockIdx.x] = s[0];
}

__global__ void scan_bsum_kernel(const int* __restrict__ bsum, int* __restrict__ bexcl,
                                 int nb, int* __restrict__ rowptr_last) {
  __shared__ int s[256];
  int t = threadIdx.x;
  int v = (t < nb) ? bsum[t] : 0;
  s[t] = v;
  __syncthreads();
  for (int off = 1; off < 256; off <<= 1) {
    int add = (t >= off) ? s[t - off] : 0;
    __syncthreads();
    s[t] += add;
    __syncthreads();
  }
  if (t < nb) bexcl[t] = s[t] - v;
  if (t == 255) *rowptr_last = s[255];
}

__global__ void rowptr_kernel(const int* __restrict__ cnt, const int* __restrict__ bexcl,
                              int* __restrict__ rowptr, int n) {
  __shared__ int s[256];
  int i = blockIdx.x * 256 + threadIdx.x;
  int t = threadIdx.x;
  int v = (i < n) ? cnt[i] : 0;
  s[t] = v;
  __syncthreads();
  for (int off = 1; off < 256; off <<= 1) {
    int add = (t >= off) ? s[t - off] : 0;
    __syncthreads();
    s[t] += add;
    __syncthreads();
  }
  if (i < n) rowptr[i] = bexcl[blockIdx.x] + s[t] - v;
}

// 2 edges/thread ILP; slot from hist's recorded arrival order (no atomic).
__global__ void fill_kernel(const int* __restrict__ src, const int* __restrict__ dst,
                            const float* __restrict__ dinv, const int* __restrict__ rowptr,
                            const int* __restrict__ eidx, int2* __restrict__ colwv, int E) {
  int e0 = (blockIdx.x * blockDim.x + threadIdx.x) * 2;
  if (e0 + 1 < E) {
    int2 s2 = *(const int2*)&src[e0];
    int2 d2 = *(const int2*)&dst[e0];
    int2 x2 = *(const int2*)&eidx[e0];
    float dsx = dinv[s2.x], ddx = dinv[d2.x];
    float dsy = dinv[s2.y], ddy = dinv[d2.y];
    int slot0 = rowptr[d2.x] + x2.x;
    int slot1 = rowptr[d2.y] + x2.y;
    int2 p0; p0.x = s2.x; p0.y = __float_as_int(dsx * ddx);
    int2 p1; p1.x = s2.y; p1.y = __float_as_int(dsy * ddy);
    colwv[slot0] = p0;
    colwv[slot1] = p1;
  } else if (e0 < E) {
    int s = src[e0], d = dst[e0];
    int slot = rowptr[d] + eidx[e0];
    int2 packed;
    packed.x = s;
    packed.y = __float_as_int(dinv[s] * dinv[d]);
    colwv[slot] = packed;
  }
}

// ---------------- fp32 -> fp16 conversion (x, once) ----------------
__global__ void f32_to_f16_kernel(const float* __restrict__ in, __half* __restrict__ out,
                                  int total4) {
  int i = blockIdx.x * blockDim.x + threadIdx.x;
  if (i >= total4) return;
  float4 v = ((const float4*)in)[i];
  half4v o;
  o.a = __floats2half2_rn(v.x, v.y);
  o.b = __floats2half2_rn(v.z, v.w);
  ((half4v*)out)[i] = o;
}

// ---------------- pack all 4 W into MFMA B-fragment order fp16 (one launch) ----------
// Wp element ((ks*8 + c)*64 + lane)*8 + j = W[k][col];
//   k = ks*32 + (lane>>4)*8 + j, col = c*16 + (lane&15)   (16x16x32_f16 B layout)
__global__ void pack_w_all_kernel(const float* __restrict__ W1, __half* __restrict__ Wp1,
                                  const float* __restrict__ W2, __half* __restrict__ Wp2,
                                  const float* __restrict__ W3, __half* __restrict__ Wp3,
                                  const float* __restrict__ W4, __half* __restrict__ Wp4) {
  int b = blockIdx.x;
  const float* W; __half* Wp; int idx;
  if (b < 32)       { W = W1; Wp = Wp1; idx = b * 256 + threadIdx.x; }
  else if (b < 96)  { W = W2; Wp = Wp2; idx = (b - 32) * 256 + threadIdx.x; }
  else if (b < 160) { W = W3; Wp = Wp3; idx = (b - 96) * 256 + threadIdx.x; }
  else              { W = W4; Wp = Wp4; idx = (b - 160) * 256 + threadIdx.x; }
  int j = idx & 7;
  int lane = (idx >> 3) & 63;
  int c = (idx >> 9) & 7;
  int ks = idx >> 12;
  int k = ks * 32 + ((lane >> 4) << 3) + j;
  int col = c * 16 + (lane & 15);
  Wp[idx] = __float2half(W[k * 128 + col]);
}

// ---------------- aggregation (fp16 in/out): agg[i] = dinv^2*h[i] + sum wv*h[col] ----------
template <int D>
__global__ __launch_bounds__(256) void aggregate_h_kernel(
    const __half* __restrict__ h, const int* __restrict__ rowptr,
    const int2* __restrict__ colwv, const float* __restrict__ dinv,
    __half* __restrict__ out, int n) {
  int wid = (blockIdx.x * 256 + threadIdx.x) >> 6;
  int lane = threadIdx.x & 63;
  if (wid >= n) return;
  float di = dinv[wid];
  float sl = di * di;
  int beg = rowptr[wid], end = rowptr[wid + 1];
  const half4v* h4 = (const half4v*)h;
  constexpr int RQ = D / 4;  // half4v per row
  float4 acc = {0.f, 0.f, 0.f, 0.f};
  constexpr int EPG = (D == 128) ? 2 : 4;
  const int sub = (D == 128) ? (lane >> 5) : (lane >> 4);
  const int lq = (D == 128) ? (lane & 31) : (lane & 15);
  for (int base = beg; base < end; base += 64) {
    int kk = base + lane;
    int c = 0; float ww = 0.f;
    if (kk < end) { int2 e = colwv[kk]; c = e.x; ww = __int_as_float(e.y); }
    int m = end - base; if (m > 64) m = 64;
    for (int t0 = 0; t0 < m; t0 += 8 * EPG) {
      half4v v[8]; float ws[8];
      #pragma unroll
      for (int u = 0; u < 8; ++u) {
        int t = t0 + EPG * u + sub;
        int cs = __shfl(c, t);
        ws[u] = __shfl(ww, t);
        v[u] = h4[(size_t)cs * RQ + lq];
      }
      #pragma unroll
      for (int u = 0; u < 8; ++u) {
        float2 fa = __half22float2(v[u].a);
        float2 fb = __half22float2(v[u].b);
        acc.x += ws[u] * fa.x; acc.y += ws[u] * fa.y;
        acc.z += ws[u] * fb.x; acc.w += ws[u] * fb.y;
      }
    }
  }
  if constexpr (D == 64) {
    acc.x += __shfl_xor(acc.x, 16); acc.y += __shfl_xor(acc.y, 16);
    acc.z += __shfl_xor(acc.z, 16); acc.w += __shfl_xor(acc.w, 16);
  }
  acc.x += __shfl_xor(acc.x, 32); acc.y += __shfl_xor(acc.y, 32);
  acc.z += __shfl_xor(acc.z, 32); acc.w += __shfl_xor(acc.w, 32);
  if (lane < RQ) {
    half4v hv = h4[(size_t)wid * RQ + lane];
    float2 fa = __half22float2(hv.a);
    float2 fb = __half22float2(hv.b);
    acc.x += sl * fa.x; acc.y += sl * fa.y; acc.z += sl * fb.x; acc.w += sl * fb.y;
    half4v o;
    o.a = __floats2half2_rn(acc.x, acc.y);
    o.b = __floats2half2_rn(acc.z, acc.w);
    ((half4v*)out)[(size_t)wid * RQ + lane] = o;
  }
}

// ---------------- MFMA GEMM: C[n,128] = relu(A[n,K] @ W + bias), fp16 in/out, f32 acc -----
template <int K>
__global__ __launch_bounds__(256) void gemm_mfma_kernel(
    const __half* __restrict__ A, const __half* __restrict__ Wp,
    const float* __restrict__ bias, __half* __restrict__ C, int n) {
  const int wave = threadIdx.x >> 6;
  const int lane = threadIdx.x & 63;
  const int r0 = blockIdx.x * 64 + wave * 16;
  const int arow = r0 + (lane & 15);
  const int kgrp = lane >> 4;
  f32x4 acc[8] = {};
  const f16x8* Wp8 = (const f16x8*)Wp;
  #pragma unroll
  for (int ks = 0; ks < K / 32; ++ks) {
    f16x8 afrag = {};
    if (arow < n) afrag = *(const f16x8*)&A[(size_t)arow * K + ks * 32 + kgrp * 8];
    #pragma unroll
    for (int c = 0; c < 8; ++c) {
      f16x8 bfrag = Wp8[(ks * 8 + c) * 64 + lane];
      acc[c] = __builtin_amdgcn_mfma_f32_16x16x32_f16(afrag, bfrag, acc[c], 0, 0, 0);
    }
  }
  const int colbase = lane & 15;
  #pragma unroll
  for (int c = 0; c < 8; ++c) {
    int col = c * 16 + colbase;
    float bv = bias[col];
    #pragma unroll
    for (int j = 0; j < 4; ++j) {
      int row = r0 + kgrp * 4 + j;
      if (row < n) C[(size_t)row * 128 + col] = __float2half(fmaxf(acc[c][j] + bv, 0.f));
    }
  }
}

// ---------------- pooling: segmented mean, 8-way node-parallel + half4v loads ----------------
__global__ __launch_bounds__(256) void pool_mean_kernel(
    const __half* __restrict__ h, const int* __restrict__ batch,
    float* __restrict__ pooled, int n) {
  int b = blockIdx.x;
  int lo = 0, hi = n;
  while (lo < hi) { int mid = (lo + hi) >> 1; if (batch[mid] < b) lo = mid + 1; else hi = mid; }
  int s = lo;
  hi = n;
  while (lo < hi) { int mid = (lo + hi) >> 1; if (batch[mid] < b + 1) lo = mid + 1; else hi = mid; }
  int e = lo;
  const half4v* h4 = (const half4v*)h;
  int q = threadIdx.x & 31;
  int r = threadIdx.x >> 5;
  float4 acc = {0.f, 0.f, 0.f, 0.f};
  for (int i = s + r; i < e; i += 8) {
    half4v v = h4[(size_t)i * 32 + q];
    float2 fa = __half22float2(v.a), fb = __half22float2(v.b);
    acc.x += fa.x; acc.y += fa.y; acc.z += fb.x; acc.w += fb.y;
  }
  __shared__ float4 red[8][32];
  red[r][q] = acc;
  __syncthreads();
  for (int off = 4; off > 0; off >>= 1) {
    if (r < off) {
      float4 o = red[r + off][q];
      acc.x += o.x; acc.y += o.y; acc.z += o.z; acc.w += o.w;
      red[r][q] = acc;
    }
    __syncthreads();
  }
  if (r == 0) {
    float c = fmaxf((float)(e - s), 1.0f);
    float4 o;
    o.x = acc.x / c; o.y = acc.y / c; o.z = acc.z / c; o.w = acc.w / c;
    ((float4*)pooled)[b * 32 + q] = o;
  }
}

// ---------------- per-graph MLP head ----------------
__global__ __launch_bounds__(128) void mlp_kernel(
    const float* __restrict__ pooled,
    const float* __restrict__ lW1, const float* __restrict__ lb1,
    const float* __restrict__ lW2, const float* __restrict__ lb2,
    const float* __restrict__ gamma, const float* __restrict__ beta,
    const float* __restrict__ rm, const float* __restrict__ rv,
    const float* __restrict__ oW, const float* __restrict__ ob,
    float* __restrict__ out, int B) {
  int b = blockIdx.x, t = threadIdx.x;
  __shared__ float p[128], h1[128];
  p[t] = pooled[b * 128 + t];
  __syncthreads();
  float a1 = lb1[t];
  for (int k = 0; k < 128; ++k) a1 += p[k] * lW1[k * 128 + t];
  h1[t] = a1;
  __syncthreads();
  if (t < 64) {
    float a2 = lb2[t];
    for (int k = 0; k < 128; ++k) a2 += h1[k] * lW2[k * 64 + t];
    a2 = (a2 - rm[t]) * gamma[t] * rsqrtf(rv[t] + 1e-5f) + beta[t];
    float hd = fmaxf(a2, 0.f);
    out[B + b * 64 + t] = hd;  // hidden, output 1
    float prod = hd * oW[t];
    #pragma unroll
    for (int off = 32; off > 0; off >>= 1) prod += __shfl_down(prod, off);
    if (t == 0) out[b] = prod + ob[0];  // out, output 0
  }
}

extern "C" void kernel_launch(void* const* d_in, const int* in_sizes, int n_in,
                              void* d_out, int out_size, void* d_ws, size_t ws_size,
                              hipStream_t stream) {
  const float* x = (const float*)d_in[0];
  const int* ei = (const int*)d_in[1];
  const int* batch = (const int*)d_in[2];
  const float* W1 = (const float*)d_in[3];  const float* b1 = (const float*)d_in[4];
  const float* W2 = (const float*)d_in[5];  const float* b2 = (const float*)d_in[6];
  const float* W3 = (const float*)d_in[7];  const float* b3 = (const float*)d_in[8];
  const float* W4 = (const float*)d_in[9];  const float* b4 = (const float*)d_in[10];
  const float* lW1 = (const float*)d_in[11]; const float* lb1 = (const float*)d_in[12];
  const float* lW2 = (const float*)d_in[13]; const float* lb2 = (const float*)d_in[14];
  const float* gamma = (const float*)d_in[15]; const float* beta = (const float*)d_in[16];
  const float* rm = (const float*)d_in[17]; const float* rv = (const float*)d_in[18];
  const float* oW = (const float*)d_in[19]; const float* ob = (const float*)d_in[20];

  const int n = in_sizes[2];
  const int E = in_sizes[1] / 2;
  const int B = out_size / 65;  // out_size = B + B*64
  const int* src = ei;
  const int* dst = ei + E;

  char* ws = (char*)d_ws;
  size_t off = 0;
  auto alloc = [&](size_t bytes) -> void* {
    void* p = ws + off;
    off += (bytes + 255) & ~(size_t)255;
    return p;
  };
  int* deg = (int*)alloc((size_t)n * 4);
  float* dinv = (float*)alloc((size_t)n * 4);
  int* rowptr = (int*)alloc((size_t)(n + 1) * 4);
  int* eidx = (int*)alloc((size_t)E * 4);
  int* bsum = (int*)alloc(256 * 4);
  int* bexcl = (int*)alloc(256 * 4);
  int2* colwv = (int2*)alloc((size_t)E * 8);
  __half* aggh = (__half*)alloc((size_t)n * 128 * 2);
  __half* hbuf = (__half*)alloc((size_t)n * 128 * 2);
  __half* xh = (__half*)alloc((size_t)n * 64 * 2);
  __half* Wp1 = (__half*)alloc(64 * 128 * 2);
  __half* Wp2 = (__half*)alloc(128 * 128 * 2);
  __half* Wp3 = (__half*)alloc(128 * 128 * 2);
  __half* Wp4 = (__half*)alloc(128 * 128 * 2);
  float* pooled = (float*)alloc((size_t)B * 128 * 4);

  const int nb = (n + 255) / 256;  // 196 blocks <= 256, fits single-block scan
  zero_kernel<<<nb, 256, 0, stream>>>(deg, n);
  hist_kernel<<<(E / 4 + 255) / 256, 256, 0, stream>>>(dst, deg, eidx, E);
  f32_to_f16_kernel<<<(n * 16 + 255) / 256, 256, 0, stream>>>(x, xh, n * 16);
  pack_w_all_kernel<<<224, 256, 0, stream>>>(W1, Wp1, W2, Wp2, W3, Wp3, W4, Wp4);
  dinv_bsum_kernel<<<nb, 256, 0, stream>>>(deg, dinv, bsum, n);
  scan_bsum_kernel<<<1, 256, 0, stream>>>(bsum, bexcl, nb, rowptr + n);
  rowptr_kernel<<<nb, 256, 0, stream>>>(deg, bexcl, rowptr, n);
  fill_kernel<<<(E / 2 + 255) / 256, 256, 0, stream>>>(src, dst, dinv, rowptr, eidx, colwv, E);

  const int aggblocks = (n + 3) / 4;      // 4 waves (nodes) per block
  const int gemmblocks = (n + 63) / 64;   // 64 rows per block

  aggregate_h_kernel<64><<<aggblocks, 256, 0, stream>>>(xh, rowptr, colwv, dinv, aggh, n);
  gemm_mfma_kernel<64><<<gemmblocks, 256, 0, stream>>>(aggh, Wp1, b1, hbuf, n);
  aggregate_h_kernel<128><<<aggblocks, 256, 0, stream>>>(hbuf, rowptr, colwv, dinv, aggh, n);
  gemm_mfma_kernel<128><<<gemmblocks, 256, 0, stream>>>(aggh, Wp2, b2, hbuf, n);
  aggregate_h_kernel<128><<<aggblocks, 256, 0, stream>>>(hbuf, rowptr, colwv, dinv, aggh, n);
  gemm_mfma_kernel<128><<<gemmblocks, 256, 0, stream>>>(aggh, Wp3, b3, hbuf, n);
  aggregate_h_kernel<128><<<aggblocks, 256, 0, stream>>>(hbuf, rowptr, colwv, dinv, aggh, n);
  gemm_mfma_kernel<128><<<gemmblocks, 256, 0, stream>>>(aggh, Wp4, b4, hbuf, n);

  pool_mean_kernel<<<B, 256, 0, stream>>>(hbuf, batch, pooled, n);
  mlp_kernel<<<B, 128, 0, stream>>>(pooled, lW1, lb1, lW2, lb2, gamma, beta, rm, rv, oW, ob,
                                    (float*)d_out, B);
}